// Round 1
// baseline (6929.050 us; speedup 1.0000x reference)
//
#include <hip/hip_runtime.h>
#include <float.h>
#include <math.h>

// ---------------------------------------------------------------------------
// GraphGeneratorX: 3-graph GraphConv network, N=100K nodes, E=3.2M edges.
// Round 0: correctness-first. segment_sum via global f32 atomics (scatter).
// Final 48-dim conv algebraically reduced: broadcast-prior aggregate == deg*prior.
// ---------------------------------------------------------------------------

__device__ __forceinline__ float eluf(float x) {
  return x > 0.0f ? x : (expf(x) - 1.0f);
}

__device__ __forceinline__ void atomicMaxF(float* addr, float val) {
  int* ia = (int*)addr;
  int old = *ia;
  while (__int_as_float(old) < val) {
    int assumed = old;
    old = atomicCAS(ia, assumed, __float_as_int(val));
    if (old == assumed) break;
  }
}

__global__ void init_feats_k(float* feats) {
  int t = threadIdx.x;
  if (t < 32) feats[t] = -FLT_MAX;
}

// ---- scatter (segment_sum) kernels: one thread per edge --------------------

__global__ void scatter2_k(const float* __restrict__ x, const int* __restrict__ ei,
                           float* __restrict__ agg, float* __restrict__ deg, int e) {
  int idx = blockIdx.x * blockDim.x + threadIdx.x;
  if (idx >= e) return;
  int s = ei[idx];
  int d = ei[e + idx];
  float2 v = ((const float2*)x)[s];
  atomicAdd(&agg[2 * d + 0], v.x);
  atomicAdd(&agg[2 * d + 1], v.y);
  if (deg) atomicAdd(&deg[d], 1.0f);
}

__global__ void scatter8_k(const float* __restrict__ x, const int* __restrict__ ei,
                           float* __restrict__ agg, int e) {
  int idx = blockIdx.x * blockDim.x + threadIdx.x;
  if (idx >= e) return;
  int s = ei[idx];
  int d = ei[e + idx];
  const float4* xp = (const float4*)(x + (size_t)s * 8);
  float4 v0 = xp[0];
  float4 v1 = xp[1];
  float* ap = agg + (size_t)d * 8;
  atomicAdd(ap + 0, v0.x); atomicAdd(ap + 1, v0.y);
  atomicAdd(ap + 2, v0.z); atomicAdd(ap + 3, v0.w);
  atomicAdd(ap + 4, v1.x); atomicAdd(ap + 5, v1.y);
  atomicAdd(ap + 6, v1.z); atomicAdd(ap + 7, v1.w);
}

__global__ void scatter16_k(const float* __restrict__ x, const int* __restrict__ ei,
                            float* __restrict__ agg, int e) {
  int idx = blockIdx.x * blockDim.x + threadIdx.x;
  if (idx >= e) return;
  int s = ei[idx];
  int d = ei[e + idx];
  const float4* xp = (const float4*)(x + (size_t)s * 16);
  float4 v0 = xp[0];
  float4 v1 = xp[1];
  float4 v2 = xp[2];
  float4 v3 = xp[3];
  float* ap = agg + (size_t)d * 16;
  atomicAdd(ap + 0,  v0.x); atomicAdd(ap + 1,  v0.y);
  atomicAdd(ap + 2,  v0.z); atomicAdd(ap + 3,  v0.w);
  atomicAdd(ap + 4,  v1.x); atomicAdd(ap + 5,  v1.y);
  atomicAdd(ap + 6,  v1.z); atomicAdd(ap + 7,  v1.w);
  atomicAdd(ap + 8,  v2.x); atomicAdd(ap + 9,  v2.y);
  atomicAdd(ap + 10, v2.z); atomicAdd(ap + 11, v2.w);
  atomicAdd(ap + 12, v3.x); atomicAdd(ap + 13, v3.y);
  atomicAdd(ap + 14, v3.z); atomicAdd(ap + 15, v3.w);
}

// ---- node-wise transform kernels -------------------------------------------

// x1 = elu(w_rel(8x2) @ agg2 + b(8) + w_root(8x2) @ xin2), store stride 8
__global__ void node_2to8_elu_k(const float* __restrict__ agg, const float* __restrict__ xin,
                                const float* __restrict__ wr, const float* __restrict__ b,
                                const float* __restrict__ wo, float* __restrict__ xout, int n) {
  int i = blockIdx.x * blockDim.x + threadIdx.x;
  if (i >= n) return;
  float2 a = ((const float2*)agg)[i];
  float2 x = ((const float2*)xin)[i];
  float out[8];
#pragma unroll
  for (int k = 0; k < 8; k++) {
    float v = wr[2 * k] * a.x + wr[2 * k + 1] * a.y + b[k]
            + wo[2 * k] * x.x + wo[2 * k + 1] * x.y;
    out[k] = eluf(v);
  }
  float4* op = (float4*)(xout + (size_t)i * 8);
  op[0] = make_float4(out[0], out[1], out[2], out[3]);
  op[1] = make_float4(out[4], out[5], out[6], out[7]);
}

// x = elu(w_rel(16x2) @ agg2 + b(16) + w_root(16x2) @ xin2), store stride 16
__global__ void node_2to16_elu_k(const float* __restrict__ agg, const float* __restrict__ xin,
                                 const float* __restrict__ wr, const float* __restrict__ b,
                                 const float* __restrict__ wo, float* __restrict__ xout, int n) {
  int i = blockIdx.x * blockDim.x + threadIdx.x;
  if (i >= n) return;
  float2 a = ((const float2*)agg)[i];
  float2 x = ((const float2*)xin)[i];
  float out[16];
#pragma unroll
  for (int k = 0; k < 16; k++) {
    float v = wr[2 * k] * a.x + wr[2 * k + 1] * a.y + b[k]
            + wo[2 * k] * x.x + wo[2 * k + 1] * x.y;
    out[k] = eluf(v);
  }
  float4* op = (float4*)(xout + (size_t)i * 16);
  op[0] = make_float4(out[0],  out[1],  out[2],  out[3]);
  op[1] = make_float4(out[4],  out[5],  out[6],  out[7]);
  op[2] = make_float4(out[8],  out[9],  out[10], out[11]);
  op[3] = make_float4(out[12], out[13], out[14], out[15]);
}

// out16 = w2r(16x8) @ agg8 + b2 + w2s(16x8) @ x8; global max-pool per channel
__global__ void conv2_pool_k(const float* __restrict__ agg, const float* __restrict__ x8,
                             const float* __restrict__ wr, const float* __restrict__ b,
                             const float* __restrict__ wo, float* __restrict__ feat, int n) {
  int i = blockIdx.x * blockDim.x + threadIdx.x;
  float out[16];
  if (i < n) {
    const float4* ap = (const float4*)(agg + (size_t)i * 8);
    const float4* xp = (const float4*)(x8 + (size_t)i * 8);
    float4 a0 = ap[0], a1 = ap[1];
    float4 x0 = xp[0], x1 = xp[1];
    float a[8] = {a0.x, a0.y, a0.z, a0.w, a1.x, a1.y, a1.z, a1.w};
    float x[8] = {x0.x, x0.y, x0.z, x0.w, x1.x, x1.y, x1.z, x1.w};
#pragma unroll
    for (int k = 0; k < 16; k++) {
      float v = b[k];
#pragma unroll
      for (int j = 0; j < 8; j++) {
        v += wr[8 * k + j] * a[j] + wo[8 * k + j] * x[j];
      }
      out[k] = v;
    }
  } else {
#pragma unroll
    for (int k = 0; k < 16; k++) out[k] = -FLT_MAX;
  }
  // wave-level max reduce, then one CAS-max per wave per channel
#pragma unroll
  for (int k = 0; k < 16; k++) {
    float v = out[k];
    for (int off = 32; off >= 1; off >>= 1) v = fmaxf(v, __shfl_xor(v, off));
    if ((threadIdx.x & 63) == 0) atomicMaxF(&feat[k], v);
  }
}

// Final conv on concat([x16, prior32]) reduced algebraically:
// out_j = b4_j + W4s[j,16:]@prior + deg_i * (W4r[j,16:]@prior)
//       + W4r[j,:16]@agg16_i + W4s[j,:16]@x16_i ;  result = sigmoid(out) + c
__global__ void final_k(const float* __restrict__ agg16, const float* __restrict__ x16,
                        const float* __restrict__ deg, const float* __restrict__ cin,
                        const float* __restrict__ feats,
                        const float* __restrict__ w4r, const float* __restrict__ b4,
                        const float* __restrict__ w4s, float* __restrict__ out, int n) {
  int i = blockIdx.x * blockDim.x + threadIdx.x;
  if (i >= n) return;
  float pr0 = 0.f, pr1 = 0.f, ps0 = 0.f, ps1 = 0.f;
#pragma unroll
  for (int k = 0; k < 32; k++) {
    float p = feats[k];   // prior = concat(o_feat, m_feat)
    pr0 += w4r[16 + k] * p;
    pr1 += w4r[48 + 16 + k] * p;
    ps0 += w4s[16 + k] * p;
    ps1 += w4s[48 + 16 + k] * p;
  }
  float d = deg[i];
  float acc0 = b4[0] + ps0 + d * pr0;
  float acc1 = b4[1] + ps1 + d * pr1;
  const float* ag = agg16 + (size_t)i * 16;
  const float* xv = x16 + (size_t)i * 16;
#pragma unroll
  for (int k = 0; k < 16; k++) {
    float a = ag[k], x = xv[k];
    acc0 += w4r[k] * a + w4s[k] * x;
    acc1 += w4r[48 + k] * a + w4s[48 + k] * x;
  }
  float2 cv = ((const float2*)cin)[i];
  float o0 = 1.0f / (1.0f + expf(-acc0)) + cv.x;
  float o1 = 1.0f / (1.0f + expf(-acc1)) + cv.y;
  ((float2*)out)[i] = make_float2(o0, o1);
}

// ---------------------------------------------------------------------------

extern "C" void kernel_launch(void* const* d_in, const int* in_sizes, int n_in,
                              void* d_out, int out_size, void* d_ws, size_t ws_size,
                              hipStream_t stream) {
  const float* o   = (const float*)d_in[0];
  const float* m   = (const float*)d_in[1];
  const float* c   = (const float*)d_in[2];
  const int* ei_o  = (const int*)d_in[3];
  const int* ei_m  = (const int*)d_in[4];
  const int* ei_c  = (const int*)d_in[5];
  const float* w1r = (const float*)d_in[6];
  const float* w1s = (const float*)d_in[7];
  const float* b1  = (const float*)d_in[8];
  const float* w2r = (const float*)d_in[9];
  const float* w2s = (const float*)d_in[10];
  const float* b2  = (const float*)d_in[11];
  const float* w3r = (const float*)d_in[12];
  const float* w3s = (const float*)d_in[13];
  const float* b3  = (const float*)d_in[14];
  const float* w4r = (const float*)d_in[15];
  const float* w4s = (const float*)d_in[16];
  const float* b4  = (const float*)d_in[17];

  const int n = in_sizes[0] / 2;       // 100000
  const int e = in_sizes[3] / 2;       // 3200000

  // workspace layout (floats): agg[n*16] | xh[n*16] | deg[n] | feats[32]
  float* agg   = (float*)d_ws;
  float* xh    = agg + (size_t)n * 16;
  float* deg   = xh + (size_t)n * 16;
  float* feats = deg + n;

  const int BS = 256;
  const int nb_e = (e + BS - 1) / BS;
  const int nb_n = (n + BS - 1) / BS;

  init_feats_k<<<1, 64, 0, stream>>>(feats);

  // ---- graph o -> feats[0:16]
  hipMemsetAsync(agg, 0, (size_t)n * 2 * sizeof(float), stream);
  scatter2_k<<<nb_e, BS, 0, stream>>>(o, ei_o, agg, nullptr, e);
  node_2to8_elu_k<<<nb_n, BS, 0, stream>>>(agg, o, w1r, b1, w1s, xh, n);
  hipMemsetAsync(agg, 0, (size_t)n * 8 * sizeof(float), stream);
  scatter8_k<<<nb_e, BS, 0, stream>>>(xh, ei_o, agg, e);
  conv2_pool_k<<<nb_n, BS, 0, stream>>>(agg, xh, w2r, b2, w2s, feats, n);

  // ---- graph m -> feats[16:32]
  hipMemsetAsync(agg, 0, (size_t)n * 2 * sizeof(float), stream);
  scatter2_k<<<nb_e, BS, 0, stream>>>(m, ei_m, agg, nullptr, e);
  node_2to8_elu_k<<<nb_n, BS, 0, stream>>>(agg, m, w1r, b1, w1s, xh, n);
  hipMemsetAsync(agg, 0, (size_t)n * 8 * sizeof(float), stream);
  scatter8_k<<<nb_e, BS, 0, stream>>>(xh, ei_m, agg, e);
  conv2_pool_k<<<nb_n, BS, 0, stream>>>(agg, xh, w2r, b2, w2s, feats + 16, n);

  // ---- graph c
  hipMemsetAsync(agg, 0, (size_t)n * 2 * sizeof(float), stream);
  hipMemsetAsync(deg, 0, (size_t)n * sizeof(float), stream);
  scatter2_k<<<nb_e, BS, 0, stream>>>(c, ei_c, agg, deg, e);
  node_2to16_elu_k<<<nb_n, BS, 0, stream>>>(agg, c, w3r, b3, w3s, xh, n);
  hipMemsetAsync(agg, 0, (size_t)n * 16 * sizeof(float), stream);
  scatter16_k<<<nb_e, BS, 0, stream>>>(xh, ei_c, agg, e);
  final_k<<<nb_n, BS, 0, stream>>>(agg, xh, deg, c, feats, w4r, b4, w4s,
                                   (float*)d_out, n);
}

// Round 2
// 1696.798 us; speedup vs baseline: 4.0836x; 4.0836x over previous
//
#include <hip/hip_runtime.h>
#include <float.h>
#include <math.h>

// ---------------------------------------------------------------------------
// GraphGeneratorX: 3-graph GraphConv network, N=100K nodes, E=3.2M edges.
// Round 2: eliminate memory-side float atomics (round-1 bottleneck: 1.6GB of
// 32B atomic transactions @670GB/s). Edges are bin-sorted by dst (98 bins of
// 1024 nodes) with cheap int-atomic reservation; aggregation happens in LDS
// (ds_add_f32) per bin with segment partials; node kernels fuse the reduce.
// ---------------------------------------------------------------------------

#define BBITS   10
#define BINSZ   1024
#define MAXP    128
#define SRCBITS 17
#define SRCMASK ((1 << SRCBITS) - 1)
#define EB      784   // blocks for hist/place edge streaming

__device__ __forceinline__ float eluf(float x) {
  return x > 0.0f ? x : (expf(x) - 1.0f);
}

__device__ __forceinline__ void atomicMaxF(float* addr, float val) {
  int* ia = (int*)addr;
  int old = *ia;
  while (__int_as_float(old) < val) {
    int assumed = old;
    old = atomicCAS(ia, assumed, __float_as_int(val));
    if (old == assumed) break;
  }
}

__global__ void init_feats_k(float* feats) {
  int t = threadIdx.x;
  if (t < 32) feats[t] = -FLT_MAX;
}

// ---- binning: histogram + scan + placement ---------------------------------

__global__ void hist_k(const int* __restrict__ ei, int e, int chunk, int P,
                       int* __restrict__ binCnt) {
  __shared__ int h[MAXP];
  int t = threadIdx.x;
  for (int i = t; i < MAXP; i += blockDim.x) h[i] = 0;
  __syncthreads();
  const int* dst = ei + e;
  int lo = blockIdx.x * chunk, hi = min(e, lo + chunk);
  for (int i = lo + t; i < hi; i += blockDim.x) atomicAdd(&h[dst[i] >> BBITS], 1);
  __syncthreads();
  for (int i = t; i < P; i += blockDim.x)
    if (h[i]) atomicAdd(&binCnt[i], h[i]);
}

__global__ void scan_k(const int* __restrict__ binCnt, int* __restrict__ binOff,
                       int* __restrict__ cursor, int P) {
  if (threadIdx.x == 0) {
    int acc = 0;
    for (int p = 0; p < P; p++) {
      binOff[p] = acc;
      cursor[p] = acc;
      acc += binCnt[p];
    }
    binOff[P] = acc;
  }
}

__global__ void place_k(const int* __restrict__ ei, int e, int chunk, int P,
                        int* __restrict__ cursor, int* __restrict__ binned) {
  __shared__ int h[MAXP];
  __shared__ int base[MAXP];
  int t = threadIdx.x;
  for (int i = t; i < MAXP; i += blockDim.x) h[i] = 0;
  __syncthreads();
  const int* src = ei;
  const int* dst = ei + e;
  int lo = blockIdx.x * chunk, hi = min(e, lo + chunk);
  for (int i = lo + t; i < hi; i += blockDim.x) atomicAdd(&h[dst[i] >> BBITS], 1);
  __syncthreads();
  for (int i = t; i < P; i += blockDim.x)
    base[i] = h[i] ? atomicAdd(&cursor[i], h[i]) : 0;
  __syncthreads();
  for (int i = t; i < MAXP; i += blockDim.x) h[i] = 0;
  __syncthreads();
  for (int i = lo + t; i < hi; i += blockDim.x) {
    int d = dst[i];
    int bb = d >> BBITS;
    int r = atomicAdd(&h[bb], 1);
    binned[base[bb] + r] = ((d & (BINSZ - 1)) << SRCBITS) | src[i];
  }
}

// ---- LDS-binned aggregation -------------------------------------------------
// grid = (S segments, P bins). Each block accumulates its bin slice in LDS and
// writes one partial slab [BINSZ*(C+DEG)] at (s*P+p).

template <int C, int S, int BLK, bool DEG>
__global__ __launch_bounds__(BLK) void agg_k(const float* __restrict__ x,
                                             const int* __restrict__ binned,
                                             const int* __restrict__ binOff,
                                             float* __restrict__ partial, int P) {
  constexpr int SLAB = BINSZ * (C + (DEG ? 1 : 0));
  __shared__ float acc[SLAB];
  int t = threadIdx.x;
  for (int i = t; i < SLAB; i += BLK) acc[i] = 0.f;
  __syncthreads();
  int p = blockIdx.y, s = blockIdx.x;
  int b0 = binOff[p], b1 = binOff[p + 1];
  int seg = (b1 - b0 + S - 1) / S;
  int lo = b0 + s * seg, hi = min(lo + seg, b1);
  for (int i = lo + t; i < hi; i += BLK) {
    int pk = binned[i];
    int sI = pk & SRCMASK;
    int loc = pk >> SRCBITS;
    float* a = acc + loc * C;
    if (C == 2) {
      float2 v = ((const float2*)x)[sI];
      atomicAdd(a + 0, v.x);
      atomicAdd(a + 1, v.y);
    } else if (C == 8) {
      const float4* xp = (const float4*)(x + (size_t)sI * 8);
      float4 v0 = xp[0], v1 = xp[1];
      atomicAdd(a + 0, v0.x); atomicAdd(a + 1, v0.y);
      atomicAdd(a + 2, v0.z); atomicAdd(a + 3, v0.w);
      atomicAdd(a + 4, v1.x); atomicAdd(a + 5, v1.y);
      atomicAdd(a + 6, v1.z); atomicAdd(a + 7, v1.w);
    } else {
      const float4* xp = (const float4*)(x + (size_t)sI * 16);
      float4 v0 = xp[0], v1 = xp[1], v2 = xp[2], v3 = xp[3];
      atomicAdd(a + 0,  v0.x); atomicAdd(a + 1,  v0.y);
      atomicAdd(a + 2,  v0.z); atomicAdd(a + 3,  v0.w);
      atomicAdd(a + 4,  v1.x); atomicAdd(a + 5,  v1.y);
      atomicAdd(a + 6,  v1.z); atomicAdd(a + 7,  v1.w);
      atomicAdd(a + 8,  v2.x); atomicAdd(a + 9,  v2.y);
      atomicAdd(a + 10, v2.z); atomicAdd(a + 11, v2.w);
      atomicAdd(a + 12, v3.x); atomicAdd(a + 13, v3.y);
      atomicAdd(a + 14, v3.z); atomicAdd(a + 15, v3.w);
    }
    if (DEG) atomicAdd(&acc[BINSZ * C + loc], 1.f);
  }
  __syncthreads();
  float4* out = (float4*)(partial + (size_t)(s * P + p) * SLAB);
  const float4* ac = (const float4*)acc;
  for (int i = t; i < SLAB / 4; i += BLK) out[i] = ac[i];
}

// ---- node transforms (fused segment-reduce) ---------------------------------

// o/m conv1: agg over 8 segments of C=2 slabs; x1 = elu(w1r@agg + b1 + w1s@x)
__global__ void node1_om_k(const float* __restrict__ partial, const float* __restrict__ xin,
                           const float* __restrict__ wr, const float* __restrict__ b,
                           const float* __restrict__ wo, float* __restrict__ xout,
                           int n, int P) {
  int i = blockIdx.x * blockDim.x + threadIdx.x;
  if (i >= n) return;
  int p = i >> BBITS, loc = i & (BINSZ - 1);
  float ax = 0.f, ay = 0.f;
#pragma unroll
  for (int s = 0; s < 8; s++) {
    float2 v = *(const float2*)(partial + (size_t)(s * P + p) * (BINSZ * 2) + loc * 2);
    ax += v.x;
    ay += v.y;
  }
  float2 xv = ((const float2*)xin)[i];
  float o_[8];
#pragma unroll
  for (int k = 0; k < 8; k++)
    o_[k] = eluf(wr[2 * k] * ax + wr[2 * k + 1] * ay + b[k] + wo[2 * k] * xv.x + wo[2 * k + 1] * xv.y);
  float4* op = (float4*)(xout + (size_t)i * 8);
  op[0] = make_float4(o_[0], o_[1], o_[2], o_[3]);
  op[1] = make_float4(o_[4], o_[5], o_[6], o_[7]);
}

// c conv1: agg over 8 segments of C=2 slabs + deg channel; x = elu(...16 ch...)
__global__ void node1_c_k(const float* __restrict__ partial, const float* __restrict__ xin,
                          const float* __restrict__ wr, const float* __restrict__ b,
                          const float* __restrict__ wo, float* __restrict__ xout,
                          float* __restrict__ deg, int n, int P) {
  int i = blockIdx.x * blockDim.x + threadIdx.x;
  if (i >= n) return;
  int p = i >> BBITS, loc = i & (BINSZ - 1);
  float ax = 0.f, ay = 0.f, dd = 0.f;
#pragma unroll
  for (int s = 0; s < 8; s++) {
    const float* sl = partial + (size_t)(s * P + p) * (BINSZ * 3);
    float2 v = *(const float2*)(sl + loc * 2);
    ax += v.x;
    ay += v.y;
    dd += sl[BINSZ * 2 + loc];
  }
  float2 xv = ((const float2*)xin)[i];
  float o_[16];
#pragma unroll
  for (int k = 0; k < 16; k++)
    o_[k] = eluf(wr[2 * k] * ax + wr[2 * k + 1] * ay + b[k] + wo[2 * k] * xv.x + wo[2 * k + 1] * xv.y);
  float4* op = (float4*)(xout + (size_t)i * 16);
  op[0] = make_float4(o_[0],  o_[1],  o_[2],  o_[3]);
  op[1] = make_float4(o_[4],  o_[5],  o_[6],  o_[7]);
  op[2] = make_float4(o_[8],  o_[9],  o_[10], o_[11]);
  op[3] = make_float4(o_[12], o_[13], o_[14], o_[15]);
  deg[i] = dd;
}

// o/m conv2 + global max pool: agg over 4 segments of C=8 slabs
__global__ void pool_k(const float* __restrict__ partial, const float* __restrict__ x8,
                       const float* __restrict__ wr, const float* __restrict__ b,
                       const float* __restrict__ wo, float* __restrict__ feat,
                       int n, int P) {
  int i = blockIdx.x * blockDim.x + threadIdx.x;
  float out[16];
  if (i < n) {
    int p = i >> BBITS, loc = i & (BINSZ - 1);
    float a[8] = {0, 0, 0, 0, 0, 0, 0, 0};
#pragma unroll
    for (int s = 0; s < 4; s++) {
      const float4* sl = (const float4*)(partial + (size_t)(s * P + p) * (BINSZ * 8) + loc * 8);
      float4 v0 = sl[0], v1 = sl[1];
      a[0] += v0.x; a[1] += v0.y; a[2] += v0.z; a[3] += v0.w;
      a[4] += v1.x; a[5] += v1.y; a[6] += v1.z; a[7] += v1.w;
    }
    const float4* xp = (const float4*)(x8 + (size_t)i * 8);
    float4 x0 = xp[0], x1 = xp[1];
    float x[8] = {x0.x, x0.y, x0.z, x0.w, x1.x, x1.y, x1.z, x1.w};
#pragma unroll
    for (int k = 0; k < 16; k++) {
      float v = b[k];
#pragma unroll
      for (int j = 0; j < 8; j++) v += wr[8 * k + j] * a[j] + wo[8 * k + j] * x[j];
      out[k] = v;
    }
  } else {
#pragma unroll
    for (int k = 0; k < 16; k++) out[k] = -FLT_MAX;
  }
#pragma unroll
  for (int k = 0; k < 16; k++) {
    float v = out[k];
    for (int off = 32; off >= 1; off >>= 1) v = fmaxf(v, __shfl_xor(v, off));
    if ((threadIdx.x & 63) == 0) atomicMaxF(&feat[k], v);
  }
}

// c final: agg over 4 segments of C=16 slabs; algebraic prior/deg reduction;
// out = sigmoid(conv4) + c
__global__ void final_k(const float* __restrict__ partial, const float* __restrict__ x16,
                        const float* __restrict__ deg, const float* __restrict__ cin,
                        const float* __restrict__ feats, const float* __restrict__ w4r,
                        const float* __restrict__ b4, const float* __restrict__ w4s,
                        float* __restrict__ out, int n, int P) {
  int i = blockIdx.x * blockDim.x + threadIdx.x;
  if (i >= n) return;
  int p = i >> BBITS, loc = i & (BINSZ - 1);
  float ag[16];
#pragma unroll
  for (int k = 0; k < 16; k++) ag[k] = 0.f;
#pragma unroll
  for (int s = 0; s < 4; s++) {
    const float4* sl = (const float4*)(partial + (size_t)(s * P + p) * (BINSZ * 16) + loc * 16);
    float4 v0 = sl[0], v1 = sl[1], v2 = sl[2], v3 = sl[3];
    ag[0]  += v0.x; ag[1]  += v0.y; ag[2]  += v0.z; ag[3]  += v0.w;
    ag[4]  += v1.x; ag[5]  += v1.y; ag[6]  += v1.z; ag[7]  += v1.w;
    ag[8]  += v2.x; ag[9]  += v2.y; ag[10] += v2.z; ag[11] += v2.w;
    ag[12] += v3.x; ag[13] += v3.y; ag[14] += v3.z; ag[15] += v3.w;
  }
  float pr0 = 0.f, pr1 = 0.f, ps0 = 0.f, ps1 = 0.f;
#pragma unroll
  for (int k = 0; k < 32; k++) {
    float pv = feats[k];
    pr0 += w4r[16 + k] * pv;
    pr1 += w4r[48 + 16 + k] * pv;
    ps0 += w4s[16 + k] * pv;
    ps1 += w4s[48 + 16 + k] * pv;
  }
  float d = deg[i];
  float acc0 = b4[0] + ps0 + d * pr0;
  float acc1 = b4[1] + ps1 + d * pr1;
  const float* xv = x16 + (size_t)i * 16;
#pragma unroll
  for (int k = 0; k < 16; k++) {
    float a = ag[k], x = xv[k];
    acc0 += w4r[k] * a + w4s[k] * x;
    acc1 += w4r[48 + k] * a + w4s[48 + k] * x;
  }
  float2 cv = ((const float2*)cin)[i];
  float o0 = 1.0f / (1.0f + expf(-acc0)) + cv.x;
  float o1 = 1.0f / (1.0f + expf(-acc1)) + cv.y;
  ((float2*)out)[i] = make_float2(o0, o1);
}

// ---- fallback path (round-0 atomic kernels, used only if ws too small) ------

__global__ void scatter2_k(const float* __restrict__ x, const int* __restrict__ ei,
                           float* __restrict__ agg, float* __restrict__ deg, int e) {
  int idx = blockIdx.x * blockDim.x + threadIdx.x;
  if (idx >= e) return;
  int s = ei[idx];
  int d = ei[e + idx];
  float2 v = ((const float2*)x)[s];
  atomicAdd(&agg[2 * d + 0], v.x);
  atomicAdd(&agg[2 * d + 1], v.y);
  if (deg) atomicAdd(&deg[d], 1.0f);
}

__global__ void scatter8_k(const float* __restrict__ x, const int* __restrict__ ei,
                           float* __restrict__ agg, int e) {
  int idx = blockIdx.x * blockDim.x + threadIdx.x;
  if (idx >= e) return;
  int s = ei[idx];
  int d = ei[e + idx];
  const float4* xp = (const float4*)(x + (size_t)s * 8);
  float4 v0 = xp[0], v1 = xp[1];
  float* ap = agg + (size_t)d * 8;
  atomicAdd(ap + 0, v0.x); atomicAdd(ap + 1, v0.y);
  atomicAdd(ap + 2, v0.z); atomicAdd(ap + 3, v0.w);
  atomicAdd(ap + 4, v1.x); atomicAdd(ap + 5, v1.y);
  atomicAdd(ap + 6, v1.z); atomicAdd(ap + 7, v1.w);
}

__global__ void scatter16_k(const float* __restrict__ x, const int* __restrict__ ei,
                            float* __restrict__ agg, int e) {
  int idx = blockIdx.x * blockDim.x + threadIdx.x;
  if (idx >= e) return;
  int s = ei[idx];
  int d = ei[e + idx];
  const float4* xp = (const float4*)(x + (size_t)s * 16);
  float4 v0 = xp[0], v1 = xp[1], v2 = xp[2], v3 = xp[3];
  float* ap = agg + (size_t)d * 16;
  atomicAdd(ap + 0,  v0.x); atomicAdd(ap + 1,  v0.y);
  atomicAdd(ap + 2,  v0.z); atomicAdd(ap + 3,  v0.w);
  atomicAdd(ap + 4,  v1.x); atomicAdd(ap + 5,  v1.y);
  atomicAdd(ap + 6,  v1.z); atomicAdd(ap + 7,  v1.w);
  atomicAdd(ap + 8,  v2.x); atomicAdd(ap + 9,  v2.y);
  atomicAdd(ap + 10, v2.z); atomicAdd(ap + 11, v2.w);
  atomicAdd(ap + 12, v3.x); atomicAdd(ap + 13, v3.y);
  atomicAdd(ap + 14, v3.z); atomicAdd(ap + 15, v3.w);
}

__global__ void node_2to8_elu_k(const float* __restrict__ agg, const float* __restrict__ xin,
                                const float* __restrict__ wr, const float* __restrict__ b,
                                const float* __restrict__ wo, float* __restrict__ xout, int n) {
  int i = blockIdx.x * blockDim.x + threadIdx.x;
  if (i >= n) return;
  float2 a = ((const float2*)agg)[i];
  float2 x = ((const float2*)xin)[i];
  float out[8];
#pragma unroll
  for (int k = 0; k < 8; k++)
    out[k] = eluf(wr[2 * k] * a.x + wr[2 * k + 1] * a.y + b[k] + wo[2 * k] * x.x + wo[2 * k + 1] * x.y);
  float4* op = (float4*)(xout + (size_t)i * 8);
  op[0] = make_float4(out[0], out[1], out[2], out[3]);
  op[1] = make_float4(out[4], out[5], out[6], out[7]);
}

__global__ void node_2to16_elu_k(const float* __restrict__ agg, const float* __restrict__ xin,
                                 const float* __restrict__ wr, const float* __restrict__ b,
                                 const float* __restrict__ wo, float* __restrict__ xout, int n) {
  int i = blockIdx.x * blockDim.x + threadIdx.x;
  if (i >= n) return;
  float2 a = ((const float2*)agg)[i];
  float2 x = ((const float2*)xin)[i];
  float out[16];
#pragma unroll
  for (int k = 0; k < 16; k++)
    out[k] = eluf(wr[2 * k] * a.x + wr[2 * k + 1] * a.y + b[k] + wo[2 * k] * x.x + wo[2 * k + 1] * x.y);
  float4* op = (float4*)(xout + (size_t)i * 16);
  op[0] = make_float4(out[0],  out[1],  out[2],  out[3]);
  op[1] = make_float4(out[4],  out[5],  out[6],  out[7]);
  op[2] = make_float4(out[8],  out[9],  out[10], out[11]);
  op[3] = make_float4(out[12], out[13], out[14], out[15]);
}

__global__ void conv2_pool_atomic_k(const float* __restrict__ agg, const float* __restrict__ x8,
                                    const float* __restrict__ wr, const float* __restrict__ b,
                                    const float* __restrict__ wo, float* __restrict__ feat, int n) {
  int i = blockIdx.x * blockDim.x + threadIdx.x;
  float out[16];
  if (i < n) {
    const float4* ap = (const float4*)(agg + (size_t)i * 8);
    const float4* xp = (const float4*)(x8 + (size_t)i * 8);
    float4 a0 = ap[0], a1 = ap[1];
    float4 x0 = xp[0], x1 = xp[1];
    float a[8] = {a0.x, a0.y, a0.z, a0.w, a1.x, a1.y, a1.z, a1.w};
    float x[8] = {x0.x, x0.y, x0.z, x0.w, x1.x, x1.y, x1.z, x1.w};
#pragma unroll
    for (int k = 0; k < 16; k++) {
      float v = b[k];
#pragma unroll
      for (int j = 0; j < 8; j++) v += wr[8 * k + j] * a[j] + wo[8 * k + j] * x[j];
      out[k] = v;
    }
  } else {
#pragma unroll
    for (int k = 0; k < 16; k++) out[k] = -FLT_MAX;
  }
#pragma unroll
  for (int k = 0; k < 16; k++) {
    float v = out[k];
    for (int off = 32; off >= 1; off >>= 1) v = fmaxf(v, __shfl_xor(v, off));
    if ((threadIdx.x & 63) == 0) atomicMaxF(&feat[k], v);
  }
}

__global__ void final_atomic_k(const float* __restrict__ agg16, const float* __restrict__ x16,
                               const float* __restrict__ deg, const float* __restrict__ cin,
                               const float* __restrict__ feats, const float* __restrict__ w4r,
                               const float* __restrict__ b4, const float* __restrict__ w4s,
                               float* __restrict__ out, int n) {
  int i = blockIdx.x * blockDim.x + threadIdx.x;
  if (i >= n) return;
  float pr0 = 0.f, pr1 = 0.f, ps0 = 0.f, ps1 = 0.f;
#pragma unroll
  for (int k = 0; k < 32; k++) {
    float pv = feats[k];
    pr0 += w4r[16 + k] * pv;
    pr1 += w4r[48 + 16 + k] * pv;
    ps0 += w4s[16 + k] * pv;
    ps1 += w4s[48 + 16 + k] * pv;
  }
  float d = deg[i];
  float acc0 = b4[0] + ps0 + d * pr0;
  float acc1 = b4[1] + ps1 + d * pr1;
  const float* ag = agg16 + (size_t)i * 16;
  const float* xv = x16 + (size_t)i * 16;
#pragma unroll
  for (int k = 0; k < 16; k++) {
    float a = ag[k], x = xv[k];
    acc0 += w4r[k] * a + w4s[k] * x;
    acc1 += w4r[48 + k] * a + w4s[48 + k] * x;
  }
  float2 cv = ((const float2*)cin)[i];
  float o0 = 1.0f / (1.0f + expf(-acc0)) + cv.x;
  float o1 = 1.0f / (1.0f + expf(-acc1)) + cv.y;
  ((float2*)out)[i] = make_float2(o0, o1);
}

// ---------------------------------------------------------------------------

extern "C" void kernel_launch(void* const* d_in, const int* in_sizes, int n_in,
                              void* d_out, int out_size, void* d_ws, size_t ws_size,
                              hipStream_t stream) {
  const float* o   = (const float*)d_in[0];
  const float* m   = (const float*)d_in[1];
  const float* c   = (const float*)d_in[2];
  const int* ei_o  = (const int*)d_in[3];
  const int* ei_m  = (const int*)d_in[4];
  const int* ei_c  = (const int*)d_in[5];
  const float* w1r = (const float*)d_in[6];
  const float* w1s = (const float*)d_in[7];
  const float* b1  = (const float*)d_in[8];
  const float* w2r = (const float*)d_in[9];
  const float* w2s = (const float*)d_in[10];
  const float* b2  = (const float*)d_in[11];
  const float* w3r = (const float*)d_in[12];
  const float* w3s = (const float*)d_in[13];
  const float* b3  = (const float*)d_in[14];
  const float* w4r = (const float*)d_in[15];
  const float* w4s = (const float*)d_in[16];
  const float* b4  = (const float*)d_in[17];

  const int n = in_sizes[0] / 2;   // 100000
  const int e = in_sizes[3] / 2;   // 3200000
  const int P = (n + BINSZ - 1) >> BBITS;

  const int BS = 256;
  const int nbn = (n + BS - 1) / BS;

  // ---- workspace layout (binned path) ----
  size_t off = 0;
  int* binned = (int*)d_ws;                         off += (size_t)e * 4;
  float* partial = (float*)((char*)d_ws + off);     off += (size_t)4 * P * BINSZ * 16 * 4;
  float* xh = (float*)((char*)d_ws + off);          off += (size_t)n * 16 * 4;
  float* deg = (float*)((char*)d_ws + off);         off += (size_t)n * 4;
  int* binCnt = (int*)((char*)d_ws + off);          off += MAXP * 4;
  int* binOff = (int*)((char*)d_ws + off);          off += (MAXP + 1) * 4;
  int* cursor = (int*)((char*)d_ws + off);          off += MAXP * 4;
  float* feats = (float*)((char*)d_ws + off);       off += 32 * 4;

  bool binned_ok = (off <= ws_size) && (P <= MAXP) && (n <= (1 << SRCBITS));

  if (!binned_ok) {
    // round-0 atomic fallback
    float* agg_f   = (float*)d_ws;
    float* xh_f    = agg_f + (size_t)n * 16;
    float* deg_f   = xh_f + (size_t)n * 16;
    float* feats_f = deg_f + n;
    const int nb_e = (e + BS - 1) / BS;
    init_feats_k<<<1, 64, 0, stream>>>(feats_f);
    hipMemsetAsync(agg_f, 0, (size_t)n * 2 * sizeof(float), stream);
    scatter2_k<<<nb_e, BS, 0, stream>>>(o, ei_o, agg_f, nullptr, e);
    node_2to8_elu_k<<<nbn, BS, 0, stream>>>(agg_f, o, w1r, b1, w1s, xh_f, n);
    hipMemsetAsync(agg_f, 0, (size_t)n * 8 * sizeof(float), stream);
    scatter8_k<<<nb_e, BS, 0, stream>>>(xh_f, ei_o, agg_f, e);
    conv2_pool_atomic_k<<<nbn, BS, 0, stream>>>(agg_f, xh_f, w2r, b2, w2s, feats_f, n);
    hipMemsetAsync(agg_f, 0, (size_t)n * 2 * sizeof(float), stream);
    scatter2_k<<<nb_e, BS, 0, stream>>>(m, ei_m, agg_f, nullptr, e);
    node_2to8_elu_k<<<nbn, BS, 0, stream>>>(agg_f, m, w1r, b1, w1s, xh_f, n);
    hipMemsetAsync(agg_f, 0, (size_t)n * 8 * sizeof(float), stream);
    scatter8_k<<<nb_e, BS, 0, stream>>>(xh_f, ei_m, agg_f, e);
    conv2_pool_atomic_k<<<nbn, BS, 0, stream>>>(agg_f, xh_f, w2r, b2, w2s, feats_f + 16, n);
    hipMemsetAsync(agg_f, 0, (size_t)n * 2 * sizeof(float), stream);
    hipMemsetAsync(deg_f, 0, (size_t)n * sizeof(float), stream);
    scatter2_k<<<nb_e, BS, 0, stream>>>(c, ei_c, agg_f, deg_f, e);
    node_2to16_elu_k<<<nbn, BS, 0, stream>>>(agg_f, c, w3r, b3, w3s, xh_f, n);
    hipMemsetAsync(agg_f, 0, (size_t)n * 16 * sizeof(float), stream);
    scatter16_k<<<nb_e, BS, 0, stream>>>(xh_f, ei_c, agg_f, e);
    final_atomic_k<<<nbn, BS, 0, stream>>>(agg_f, xh_f, deg_f, c, feats_f, w4r, b4, w4s,
                                           (float*)d_out, n);
    return;
  }

  const int chunk = (e + EB - 1) / EB;

  init_feats_k<<<1, 64, 0, stream>>>(feats);

  // ---- graph o -> feats[0:16]
  hipMemsetAsync(binCnt, 0, P * sizeof(int), stream);
  hist_k<<<EB, BS, 0, stream>>>(ei_o, e, chunk, P, binCnt);
  scan_k<<<1, 1, 0, stream>>>(binCnt, binOff, cursor, P);
  place_k<<<EB, BS, 0, stream>>>(ei_o, e, chunk, P, cursor, binned);
  agg_k<2, 8, 256, false><<<dim3(8, P), 256, 0, stream>>>(o, binned, binOff, partial, P);
  node1_om_k<<<nbn, BS, 0, stream>>>(partial, o, w1r, b1, w1s, xh, n, P);
  agg_k<8, 4, 512, false><<<dim3(4, P), 512, 0, stream>>>(xh, binned, binOff, partial, P);
  pool_k<<<nbn, BS, 0, stream>>>(partial, xh, w2r, b2, w2s, feats, n, P);

  // ---- graph m -> feats[16:32]
  hipMemsetAsync(binCnt, 0, P * sizeof(int), stream);
  hist_k<<<EB, BS, 0, stream>>>(ei_m, e, chunk, P, binCnt);
  scan_k<<<1, 1, 0, stream>>>(binCnt, binOff, cursor, P);
  place_k<<<EB, BS, 0, stream>>>(ei_m, e, chunk, P, cursor, binned);
  agg_k<2, 8, 256, false><<<dim3(8, P), 256, 0, stream>>>(m, binned, binOff, partial, P);
  node1_om_k<<<nbn, BS, 0, stream>>>(partial, m, w1r, b1, w1s, xh, n, P);
  agg_k<8, 4, 512, false><<<dim3(4, P), 512, 0, stream>>>(xh, binned, binOff, partial, P);
  pool_k<<<nbn, BS, 0, stream>>>(partial, xh, w2r, b2, w2s, feats + 16, n, P);

  // ---- graph c
  hipMemsetAsync(binCnt, 0, P * sizeof(int), stream);
  hist_k<<<EB, BS, 0, stream>>>(ei_c, e, chunk, P, binCnt);
  scan_k<<<1, 1, 0, stream>>>(binCnt, binOff, cursor, P);
  place_k<<<EB, BS, 0, stream>>>(ei_c, e, chunk, P, cursor, binned);
  agg_k<2, 8, 256, true><<<dim3(8, P), 256, 0, stream>>>(c, binned, binOff, partial, P);
  node1_c_k<<<nbn, BS, 0, stream>>>(partial, c, w3r, b3, w3s, xh, deg, n, P);
  agg_k<16, 4, 512, false><<<dim3(4, P), 512, 0, stream>>>(xh, binned, binOff, partial, P);
  final_k<<<nbn, BS, 0, stream>>>(partial, xh, deg, c, feats, w4r, b4, w4s,
                                  (float*)d_out, n, P);
}

// Round 3
// 1619.992 us; speedup vs baseline: 4.2772x; 1.0474x over previous
//
#include <hip/hip_runtime.h>
#include <float.h>
#include <math.h>

// ---------------------------------------------------------------------------
// GraphGeneratorX: 3-graph GraphConv network, N=100K nodes, E=3.2M edges.
// Round 3: fix round-2 agg_k limiters (32-way LDS bank conflict from stride-16
// ds_add; 25% occupancy from 64KB slabs). Channel-split: 4 lanes/edge each
// doing a float4/float2 slice -> 4-way conflict; BINSZ 1024->256 -> 16KB slab,
// 8 blocks/CU. Partial-sum layout unchanged (node kernels fuse the reduce).
// ---------------------------------------------------------------------------

#define BBITS   8
#define BINSZ   256
#define MAXP    512
#define SRCBITS 17
#define SRCMASK ((1 << SRCBITS) - 1)
#define EB      512   // blocks for hist/place edge streaming

__device__ __forceinline__ float eluf(float x) {
  return x > 0.0f ? x : (expf(x) - 1.0f);
}

__device__ __forceinline__ void atomicMaxF(float* addr, float val) {
  int* ia = (int*)addr;
  int old = *ia;
  while (__int_as_float(old) < val) {
    int assumed = old;
    old = atomicCAS(ia, assumed, __float_as_int(val));
    if (old == assumed) break;
  }
}

__global__ void init_feats_k(float* feats) {
  int t = threadIdx.x;
  if (t < 32) feats[t] = -FLT_MAX;
}

// ---- binning: histogram + scan + placement ---------------------------------

__global__ void hist_k(const int* __restrict__ ei, int e, int chunk, int P,
                       int* __restrict__ binCnt) {
  __shared__ int h[MAXP];
  int t = threadIdx.x;
  for (int i = t; i < MAXP; i += blockDim.x) h[i] = 0;
  __syncthreads();
  const int* dst = ei + e;
  int lo = blockIdx.x * chunk, hi = min(e, lo + chunk);
  for (int i = lo + t; i < hi; i += blockDim.x) atomicAdd(&h[dst[i] >> BBITS], 1);
  __syncthreads();
  for (int i = t; i < P; i += blockDim.x)
    if (h[i]) atomicAdd(&binCnt[i], h[i]);
}

__global__ void scan_k(const int* __restrict__ binCnt, int* __restrict__ binOff,
                       int* __restrict__ cursor, int P) {
  if (threadIdx.x == 0) {
    int acc = 0;
    for (int p = 0; p < P; p++) {
      binOff[p] = acc;
      cursor[p] = acc;
      acc += binCnt[p];
    }
    binOff[P] = acc;
  }
}

__global__ void place_k(const int* __restrict__ ei, int e, int chunk, int P,
                        int* __restrict__ cursor, int* __restrict__ binned) {
  __shared__ int h[MAXP];
  __shared__ int base[MAXP];
  int t = threadIdx.x;
  for (int i = t; i < MAXP; i += blockDim.x) h[i] = 0;
  __syncthreads();
  const int* src = ei;
  const int* dst = ei + e;
  int lo = blockIdx.x * chunk, hi = min(e, lo + chunk);
  for (int i = lo + t; i < hi; i += blockDim.x) atomicAdd(&h[dst[i] >> BBITS], 1);
  __syncthreads();
  for (int i = t; i < P; i += blockDim.x)
    base[i] = h[i] ? atomicAdd(&cursor[i], h[i]) : 0;
  __syncthreads();
  for (int i = t; i < MAXP; i += blockDim.x) h[i] = 0;
  __syncthreads();
  for (int i = lo + t; i < hi; i += blockDim.x) {
    int d = dst[i];
    int bb = d >> BBITS;
    int r = atomicAdd(&h[bb], 1);
    binned[base[bb] + r] = ((d & (BINSZ - 1)) << SRCBITS) | src[i];
  }
}

// ---- LDS-binned aggregation -------------------------------------------------
// grid = (S segments, P bins). LPE lanes cooperate on one edge, each lane
// handling C/LPE channels (slice load + ds_add). Bank index spreads over
// 16 banks -> ~4-way conflict instead of round-2's 32-way.

template <int C, int LPE, int S, int BLK, bool DEG>
__global__ __launch_bounds__(BLK) void agg_k(const float* __restrict__ x,
                                             const int* __restrict__ binned,
                                             const int* __restrict__ binOff,
                                             float* __restrict__ partial, int P) {
  constexpr int SLAB = BINSZ * (C + (DEG ? 1 : 0));
  constexpr int CL = C / LPE;     // channels per lane
  constexpr int GPB = BLK / LPE;  // edge groups per block
  __shared__ float acc[SLAB];
  int t = threadIdx.x;
  for (int i = t; i < SLAB; i += BLK) acc[i] = 0.f;
  __syncthreads();
  int p = blockIdx.y, s = blockIdx.x;
  int b0 = binOff[p], b1 = binOff[p + 1];
  int seg = (b1 - b0 + S - 1) / S;
  int lo = b0 + s * seg, hi = min(lo + seg, b1);
  int g = t / LPE, j = t % LPE;
#pragma unroll 2
  for (int e = lo + g; e < hi; e += GPB) {
    int pk = binned[e];
    int sI = pk & SRCMASK;
    int loc = pk >> SRCBITS;
    float* a = acc + loc * C + j * CL;
    if (CL == 2) {
      float2 v = *(const float2*)(x + (size_t)sI * C + j * 2);
      atomicAdd(a + 0, v.x);
      atomicAdd(a + 1, v.y);
    } else {
      float4 v = *(const float4*)(x + (size_t)sI * C + j * 4);
      atomicAdd(a + 0, v.x);
      atomicAdd(a + 1, v.y);
      atomicAdd(a + 2, v.z);
      atomicAdd(a + 3, v.w);
    }
    if (DEG && j == 0) atomicAdd(&acc[BINSZ * C + loc], 1.f);
  }
  __syncthreads();
  float4* out = (float4*)(partial + (size_t)(s * P + p) * SLAB);
  const float4* ac = (const float4*)acc;
  for (int i = t; i < SLAB / 4; i += BLK) out[i] = ac[i];
}

// ---- node transforms (fused segment-reduce) ---------------------------------

// o/m conv1: agg over 8 segments of C=2 slabs; x1 = elu(w1r@agg + b1 + w1s@x)
__global__ void node1_om_k(const float* __restrict__ partial, const float* __restrict__ xin,
                           const float* __restrict__ wr, const float* __restrict__ b,
                           const float* __restrict__ wo, float* __restrict__ xout,
                           int n, int P) {
  int i = blockIdx.x * blockDim.x + threadIdx.x;
  if (i >= n) return;
  int p = i >> BBITS, loc = i & (BINSZ - 1);
  float ax = 0.f, ay = 0.f;
#pragma unroll
  for (int s = 0; s < 8; s++) {
    float2 v = *(const float2*)(partial + (size_t)(s * P + p) * (BINSZ * 2) + loc * 2);
    ax += v.x;
    ay += v.y;
  }
  float2 xv = ((const float2*)xin)[i];
  float o_[8];
#pragma unroll
  for (int k = 0; k < 8; k++)
    o_[k] = eluf(wr[2 * k] * ax + wr[2 * k + 1] * ay + b[k] + wo[2 * k] * xv.x + wo[2 * k + 1] * xv.y);
  float4* op = (float4*)(xout + (size_t)i * 8);
  op[0] = make_float4(o_[0], o_[1], o_[2], o_[3]);
  op[1] = make_float4(o_[4], o_[5], o_[6], o_[7]);
}

// c conv1: agg over 8 segments of C=2 slabs + deg channel; x = elu(...16 ch...)
__global__ void node1_c_k(const float* __restrict__ partial, const float* __restrict__ xin,
                          const float* __restrict__ wr, const float* __restrict__ b,
                          const float* __restrict__ wo, float* __restrict__ xout,
                          float* __restrict__ deg, int n, int P) {
  int i = blockIdx.x * blockDim.x + threadIdx.x;
  if (i >= n) return;
  int p = i >> BBITS, loc = i & (BINSZ - 1);
  float ax = 0.f, ay = 0.f, dd = 0.f;
#pragma unroll
  for (int s = 0; s < 8; s++) {
    const float* sl = partial + (size_t)(s * P + p) * (BINSZ * 3);
    float2 v = *(const float2*)(sl + loc * 2);
    ax += v.x;
    ay += v.y;
    dd += sl[BINSZ * 2 + loc];
  }
  float2 xv = ((const float2*)xin)[i];
  float o_[16];
#pragma unroll
  for (int k = 0; k < 16; k++)
    o_[k] = eluf(wr[2 * k] * ax + wr[2 * k + 1] * ay + b[k] + wo[2 * k] * xv.x + wo[2 * k + 1] * xv.y);
  float4* op = (float4*)(xout + (size_t)i * 16);
  op[0] = make_float4(o_[0],  o_[1],  o_[2],  o_[3]);
  op[1] = make_float4(o_[4],  o_[5],  o_[6],  o_[7]);
  op[2] = make_float4(o_[8],  o_[9],  o_[10], o_[11]);
  op[3] = make_float4(o_[12], o_[13], o_[14], o_[15]);
  deg[i] = dd;
}

// o/m conv2 + global max pool: agg over 4 segments of C=8 slabs
__global__ void pool_k(const float* __restrict__ partial, const float* __restrict__ x8,
                       const float* __restrict__ wr, const float* __restrict__ b,
                       const float* __restrict__ wo, float* __restrict__ feat,
                       int n, int P) {
  int i = blockIdx.x * blockDim.x + threadIdx.x;
  float out[16];
  if (i < n) {
    int p = i >> BBITS, loc = i & (BINSZ - 1);
    float a[8] = {0, 0, 0, 0, 0, 0, 0, 0};
#pragma unroll
    for (int s = 0; s < 4; s++) {
      const float4* sl = (const float4*)(partial + (size_t)(s * P + p) * (BINSZ * 8) + loc * 8);
      float4 v0 = sl[0], v1 = sl[1];
      a[0] += v0.x; a[1] += v0.y; a[2] += v0.z; a[3] += v0.w;
      a[4] += v1.x; a[5] += v1.y; a[6] += v1.z; a[7] += v1.w;
    }
    const float4* xp = (const float4*)(x8 + (size_t)i * 8);
    float4 x0 = xp[0], x1 = xp[1];
    float x[8] = {x0.x, x0.y, x0.z, x0.w, x1.x, x1.y, x1.z, x1.w};
#pragma unroll
    for (int k = 0; k < 16; k++) {
      float v = b[k];
#pragma unroll
      for (int j = 0; j < 8; j++) v += wr[8 * k + j] * a[j] + wo[8 * k + j] * x[j];
      out[k] = v;
    }
  } else {
#pragma unroll
    for (int k = 0; k < 16; k++) out[k] = -FLT_MAX;
  }
#pragma unroll
  for (int k = 0; k < 16; k++) {
    float v = out[k];
    for (int off = 32; off >= 1; off >>= 1) v = fmaxf(v, __shfl_xor(v, off));
    if ((threadIdx.x & 63) == 0) atomicMaxF(&feat[k], v);
  }
}

// c final: agg over 4 segments of C=16 slabs; algebraic prior/deg reduction;
// out = sigmoid(conv4) + c
__global__ void final_k(const float* __restrict__ partial, const float* __restrict__ x16,
                        const float* __restrict__ deg, const float* __restrict__ cin,
                        const float* __restrict__ feats, const float* __restrict__ w4r,
                        const float* __restrict__ b4, const float* __restrict__ w4s,
                        float* __restrict__ out, int n, int P) {
  int i = blockIdx.x * blockDim.x + threadIdx.x;
  if (i >= n) return;
  int p = i >> BBITS, loc = i & (BINSZ - 1);
  float ag[16];
#pragma unroll
  for (int k = 0; k < 16; k++) ag[k] = 0.f;
#pragma unroll
  for (int s = 0; s < 4; s++) {
    const float4* sl = (const float4*)(partial + (size_t)(s * P + p) * (BINSZ * 16) + loc * 16);
    float4 v0 = sl[0], v1 = sl[1], v2 = sl[2], v3 = sl[3];
    ag[0]  += v0.x; ag[1]  += v0.y; ag[2]  += v0.z; ag[3]  += v0.w;
    ag[4]  += v1.x; ag[5]  += v1.y; ag[6]  += v1.z; ag[7]  += v1.w;
    ag[8]  += v2.x; ag[9]  += v2.y; ag[10] += v2.z; ag[11] += v2.w;
    ag[12] += v3.x; ag[13] += v3.y; ag[14] += v3.z; ag[15] += v3.w;
  }
  float pr0 = 0.f, pr1 = 0.f, ps0 = 0.f, ps1 = 0.f;
#pragma unroll
  for (int k = 0; k < 32; k++) {
    float pv = feats[k];
    pr0 += w4r[16 + k] * pv;
    pr1 += w4r[48 + 16 + k] * pv;
    ps0 += w4s[16 + k] * pv;
    ps1 += w4s[48 + 16 + k] * pv;
  }
  float d = deg[i];
  float acc0 = b4[0] + ps0 + d * pr0;
  float acc1 = b4[1] + ps1 + d * pr1;
  const float* xv = x16 + (size_t)i * 16;
#pragma unroll
  for (int k = 0; k < 16; k++) {
    float a = ag[k], x = xv[k];
    acc0 += w4r[k] * a + w4s[k] * x;
    acc1 += w4r[48 + k] * a + w4s[48 + k] * x;
  }
  float2 cv = ((const float2*)cin)[i];
  float o0 = 1.0f / (1.0f + expf(-acc0)) + cv.x;
  float o1 = 1.0f / (1.0f + expf(-acc1)) + cv.y;
  ((float2*)out)[i] = make_float2(o0, o1);
}

// ---- fallback path (round-0 atomic kernels, used only if ws too small) ------

__global__ void scatter2_k(const float* __restrict__ x, const int* __restrict__ ei,
                           float* __restrict__ agg, float* __restrict__ deg, int e) {
  int idx = blockIdx.x * blockDim.x + threadIdx.x;
  if (idx >= e) return;
  int s = ei[idx];
  int d = ei[e + idx];
  float2 v = ((const float2*)x)[s];
  atomicAdd(&agg[2 * d + 0], v.x);
  atomicAdd(&agg[2 * d + 1], v.y);
  if (deg) atomicAdd(&deg[d], 1.0f);
}

__global__ void scatter8_k(const float* __restrict__ x, const int* __restrict__ ei,
                           float* __restrict__ agg, int e) {
  int idx = blockIdx.x * blockDim.x + threadIdx.x;
  if (idx >= e) return;
  int s = ei[idx];
  int d = ei[e + idx];
  const float4* xp = (const float4*)(x + (size_t)s * 8);
  float4 v0 = xp[0], v1 = xp[1];
  float* ap = agg + (size_t)d * 8;
  atomicAdd(ap + 0, v0.x); atomicAdd(ap + 1, v0.y);
  atomicAdd(ap + 2, v0.z); atomicAdd(ap + 3, v0.w);
  atomicAdd(ap + 4, v1.x); atomicAdd(ap + 5, v1.y);
  atomicAdd(ap + 6, v1.z); atomicAdd(ap + 7, v1.w);
}

__global__ void scatter16_k(const float* __restrict__ x, const int* __restrict__ ei,
                            float* __restrict__ agg, int e) {
  int idx = blockIdx.x * blockDim.x + threadIdx.x;
  if (idx >= e) return;
  int s = ei[idx];
  int d = ei[e + idx];
  const float4* xp = (const float4*)(x + (size_t)s * 16);
  float4 v0 = xp[0], v1 = xp[1], v2 = xp[2], v3 = xp[3];
  float* ap = agg + (size_t)d * 16;
  atomicAdd(ap + 0,  v0.x); atomicAdd(ap + 1,  v0.y);
  atomicAdd(ap + 2,  v0.z); atomicAdd(ap + 3,  v0.w);
  atomicAdd(ap + 4,  v1.x); atomicAdd(ap + 5,  v1.y);
  atomicAdd(ap + 6,  v1.z); atomicAdd(ap + 7,  v1.w);
  atomicAdd(ap + 8,  v2.x); atomicAdd(ap + 9,  v2.y);
  atomicAdd(ap + 10, v2.z); atomicAdd(ap + 11, v2.w);
  atomicAdd(ap + 12, v3.x); atomicAdd(ap + 13, v3.y);
  atomicAdd(ap + 14, v3.z); atomicAdd(ap + 15, v3.w);
}

__global__ void node_2to8_elu_k(const float* __restrict__ agg, const float* __restrict__ xin,
                                const float* __restrict__ wr, const float* __restrict__ b,
                                const float* __restrict__ wo, float* __restrict__ xout, int n) {
  int i = blockIdx.x * blockDim.x + threadIdx.x;
  if (i >= n) return;
  float2 a = ((const float2*)agg)[i];
  float2 x = ((const float2*)xin)[i];
  float out[8];
#pragma unroll
  for (int k = 0; k < 8; k++)
    out[k] = eluf(wr[2 * k] * a.x + wr[2 * k + 1] * a.y + b[k] + wo[2 * k] * x.x + wo[2 * k + 1] * x.y);
  float4* op = (float4*)(xout + (size_t)i * 8);
  op[0] = make_float4(out[0], out[1], out[2], out[3]);
  op[1] = make_float4(out[4], out[5], out[6], out[7]);
}

__global__ void node_2to16_elu_k(const float* __restrict__ agg, const float* __restrict__ xin,
                                 const float* __restrict__ wr, const float* __restrict__ b,
                                 const float* __restrict__ wo, float* __restrict__ xout, int n) {
  int i = blockIdx.x * blockDim.x + threadIdx.x;
  if (i >= n) return;
  float2 a = ((const float2*)agg)[i];
  float2 x = ((const float2*)xin)[i];
  float out[16];
#pragma unroll
  for (int k = 0; k < 16; k++)
    out[k] = eluf(wr[2 * k] * a.x + wr[2 * k + 1] * a.y + b[k] + wo[2 * k] * x.x + wo[2 * k + 1] * x.y);
  float4* op = (float4*)(xout + (size_t)i * 16);
  op[0] = make_float4(out[0],  out[1],  out[2],  out[3]);
  op[1] = make_float4(out[4],  out[5],  out[6],  out[7]);
  op[2] = make_float4(out[8],  out[9],  out[10], out[11]);
  op[3] = make_float4(out[12], out[13], out[14], out[15]);
}

__global__ void conv2_pool_atomic_k(const float* __restrict__ agg, const float* __restrict__ x8,
                                    const float* __restrict__ wr, const float* __restrict__ b,
                                    const float* __restrict__ wo, float* __restrict__ feat, int n) {
  int i = blockIdx.x * blockDim.x + threadIdx.x;
  float out[16];
  if (i < n) {
    const float4* ap = (const float4*)(agg + (size_t)i * 8);
    const float4* xp = (const float4*)(x8 + (size_t)i * 8);
    float4 a0 = ap[0], a1 = ap[1];
    float4 x0 = xp[0], x1 = xp[1];
    float a[8] = {a0.x, a0.y, a0.z, a0.w, a1.x, a1.y, a1.z, a1.w};
    float x[8] = {x0.x, x0.y, x0.z, x0.w, x1.x, x1.y, x1.z, x1.w};
#pragma unroll
    for (int k = 0; k < 16; k++) {
      float v = b[k];
#pragma unroll
      for (int j = 0; j < 8; j++) v += wr[8 * k + j] * a[j] + wo[8 * k + j] * x[j];
      out[k] = v;
    }
  } else {
#pragma unroll
    for (int k = 0; k < 16; k++) out[k] = -FLT_MAX;
  }
#pragma unroll
  for (int k = 0; k < 16; k++) {
    float v = out[k];
    for (int off = 32; off >= 1; off >>= 1) v = fmaxf(v, __shfl_xor(v, off));
    if ((threadIdx.x & 63) == 0) atomicMaxF(&feat[k], v);
  }
}

__global__ void final_atomic_k(const float* __restrict__ agg16, const float* __restrict__ x16,
                               const float* __restrict__ deg, const float* __restrict__ cin,
                               const float* __restrict__ feats, const float* __restrict__ w4r,
                               const float* __restrict__ b4, const float* __restrict__ w4s,
                               float* __restrict__ out, int n) {
  int i = blockIdx.x * blockDim.x + threadIdx.x;
  if (i >= n) return;
  float pr0 = 0.f, pr1 = 0.f, ps0 = 0.f, ps1 = 0.f;
#pragma unroll
  for (int k = 0; k < 32; k++) {
    float pv = feats[k];
    pr0 += w4r[16 + k] * pv;
    pr1 += w4r[48 + 16 + k] * pv;
    ps0 += w4s[16 + k] * pv;
    ps1 += w4s[48 + 16 + k] * pv;
  }
  float d = deg[i];
  float acc0 = b4[0] + ps0 + d * pr0;
  float acc1 = b4[1] + ps1 + d * pr1;
  const float* ag = agg16 + (size_t)i * 16;
  const float* xv = x16 + (size_t)i * 16;
#pragma unroll
  for (int k = 0; k < 16; k++) {
    float a = ag[k], x = xv[k];
    acc0 += w4r[k] * a + w4s[k] * x;
    acc1 += w4r[48 + k] * a + w4s[48 + k] * x;
  }
  float2 cv = ((const float2*)cin)[i];
  float o0 = 1.0f / (1.0f + expf(-acc0)) + cv.x;
  float o1 = 1.0f / (1.0f + expf(-acc1)) + cv.y;
  ((float2*)out)[i] = make_float2(o0, o1);
}

// ---------------------------------------------------------------------------

extern "C" void kernel_launch(void* const* d_in, const int* in_sizes, int n_in,
                              void* d_out, int out_size, void* d_ws, size_t ws_size,
                              hipStream_t stream) {
  const float* o   = (const float*)d_in[0];
  const float* m   = (const float*)d_in[1];
  const float* c   = (const float*)d_in[2];
  const int* ei_o  = (const int*)d_in[3];
  const int* ei_m  = (const int*)d_in[4];
  const int* ei_c  = (const int*)d_in[5];
  const float* w1r = (const float*)d_in[6];
  const float* w1s = (const float*)d_in[7];
  const float* b1  = (const float*)d_in[8];
  const float* w2r = (const float*)d_in[9];
  const float* w2s = (const float*)d_in[10];
  const float* b2  = (const float*)d_in[11];
  const float* w3r = (const float*)d_in[12];
  const float* w3s = (const float*)d_in[13];
  const float* b3  = (const float*)d_in[14];
  const float* w4r = (const float*)d_in[15];
  const float* w4s = (const float*)d_in[16];
  const float* b4  = (const float*)d_in[17];

  const int n = in_sizes[0] / 2;   // 100000
  const int e = in_sizes[3] / 2;   // 3200000
  const int P = (n + BINSZ - 1) >> BBITS;

  const int BS = 256;
  const int nbn = (n + BS - 1) / BS;

  // ---- workspace layout (binned path) ----
  size_t off = 0;
  int* binned = (int*)d_ws;                         off += (size_t)e * 4;
  float* partial = (float*)((char*)d_ws + off);     off += (size_t)4 * P * BINSZ * 16 * 4;
  float* xh = (float*)((char*)d_ws + off);          off += (size_t)n * 16 * 4;
  float* deg = (float*)((char*)d_ws + off);         off += (size_t)n * 4;
  int* binCnt = (int*)((char*)d_ws + off);          off += MAXP * 4;
  int* binOff = (int*)((char*)d_ws + off);          off += (MAXP + 1) * 4;
  int* cursor = (int*)((char*)d_ws + off);          off += MAXP * 4;
  float* feats = (float*)((char*)d_ws + off);       off += 32 * 4;

  bool binned_ok = (off <= ws_size) && (P <= MAXP) && (n <= (1 << SRCBITS));

  if (!binned_ok) {
    // round-0 atomic fallback
    float* agg_f   = (float*)d_ws;
    float* xh_f    = agg_f + (size_t)n * 16;
    float* deg_f   = xh_f + (size_t)n * 16;
    float* feats_f = deg_f + n;
    const int nb_e = (e + BS - 1) / BS;
    init_feats_k<<<1, 64, 0, stream>>>(feats_f);
    hipMemsetAsync(agg_f, 0, (size_t)n * 2 * sizeof(float), stream);
    scatter2_k<<<nb_e, BS, 0, stream>>>(o, ei_o, agg_f, nullptr, e);
    node_2to8_elu_k<<<nbn, BS, 0, stream>>>(agg_f, o, w1r, b1, w1s, xh_f, n);
    hipMemsetAsync(agg_f, 0, (size_t)n * 8 * sizeof(float), stream);
    scatter8_k<<<nb_e, BS, 0, stream>>>(xh_f, ei_o, agg_f, e);
    conv2_pool_atomic_k<<<nbn, BS, 0, stream>>>(agg_f, xh_f, w2r, b2, w2s, feats_f, n);
    hipMemsetAsync(agg_f, 0, (size_t)n * 2 * sizeof(float), stream);
    scatter2_k<<<nb_e, BS, 0, stream>>>(m, ei_m, agg_f, nullptr, e);
    node_2to8_elu_k<<<nbn, BS, 0, stream>>>(agg_f, m, w1r, b1, w1s, xh_f, n);
    hipMemsetAsync(agg_f, 0, (size_t)n * 8 * sizeof(float), stream);
    scatter8_k<<<nb_e, BS, 0, stream>>>(xh_f, ei_m, agg_f, e);
    conv2_pool_atomic_k<<<nbn, BS, 0, stream>>>(agg_f, xh_f, w2r, b2, w2s, feats_f + 16, n);
    hipMemsetAsync(agg_f, 0, (size_t)n * 2 * sizeof(float), stream);
    hipMemsetAsync(deg_f, 0, (size_t)n * sizeof(float), stream);
    scatter2_k<<<nb_e, BS, 0, stream>>>(c, ei_c, agg_f, deg_f, e);
    node_2to16_elu_k<<<nbn, BS, 0, stream>>>(agg_f, c, w3r, b3, w3s, xh_f, n);
    hipMemsetAsync(agg_f, 0, (size_t)n * 16 * sizeof(float), stream);
    scatter16_k<<<nb_e, BS, 0, stream>>>(xh_f, ei_c, agg_f, e);
    final_atomic_k<<<nbn, BS, 0, stream>>>(agg_f, xh_f, deg_f, c, feats_f, w4r, b4, w4s,
                                           (float*)d_out, n);
    return;
  }

  const int chunk = (e + EB - 1) / EB;

  init_feats_k<<<1, 64, 0, stream>>>(feats);

  // ---- graph o -> feats[0:16]
  hipMemsetAsync(binCnt, 0, P * sizeof(int), stream);
  hist_k<<<EB, BS, 0, stream>>>(ei_o, e, chunk, P, binCnt);
  scan_k<<<1, 1, 0, stream>>>(binCnt, binOff, cursor, P);
  place_k<<<EB, BS, 0, stream>>>(ei_o, e, chunk, P, cursor, binned);
  agg_k<2, 1, 8, 256, false><<<dim3(8, P), 256, 0, stream>>>(o, binned, binOff, partial, P);
  node1_om_k<<<nbn, BS, 0, stream>>>(partial, o, w1r, b1, w1s, xh, n, P);
  agg_k<8, 4, 4, 256, false><<<dim3(4, P), 256, 0, stream>>>(xh, binned, binOff, partial, P);
  pool_k<<<nbn, BS, 0, stream>>>(partial, xh, w2r, b2, w2s, feats, n, P);

  // ---- graph m -> feats[16:32]
  hipMemsetAsync(binCnt, 0, P * sizeof(int), stream);
  hist_k<<<EB, BS, 0, stream>>>(ei_m, e, chunk, P, binCnt);
  scan_k<<<1, 1, 0, stream>>>(binCnt, binOff, cursor, P);
  place_k<<<EB, BS, 0, stream>>>(ei_m, e, chunk, P, cursor, binned);
  agg_k<2, 1, 8, 256, false><<<dim3(8, P), 256, 0, stream>>>(m, binned, binOff, partial, P);
  node1_om_k<<<nbn, BS, 0, stream>>>(partial, m, w1r, b1, w1s, xh, n, P);
  agg_k<8, 4, 4, 256, false><<<dim3(4, P), 256, 0, stream>>>(xh, binned, binOff, partial, P);
  pool_k<<<nbn, BS, 0, stream>>>(partial, xh, w2r, b2, w2s, feats + 16, n, P);

  // ---- graph c
  hipMemsetAsync(binCnt, 0, P * sizeof(int), stream);
  hist_k<<<EB, BS, 0, stream>>>(ei_c, e, chunk, P, binCnt);
  scan_k<<<1, 1, 0, stream>>>(binCnt, binOff, cursor, P);
  place_k<<<EB, BS, 0, stream>>>(ei_c, e, chunk, P, cursor, binned);
  agg_k<2, 1, 8, 256, true><<<dim3(8, P), 256, 0, stream>>>(c, binned, binOff, partial, P);
  node1_c_k<<<nbn, BS, 0, stream>>>(partial, c, w3r, b3, w3s, xh, deg, n, P);
  agg_k<16, 4, 4, 256, false><<<dim3(4, P), 256, 0, stream>>>(xh, binned, binOff, partial, P);
  final_k<<<nbn, BS, 0, stream>>>(partial, xh, deg, c, feats, w4r, b4, w4s,
                                  (float*)d_out, n, P);
}

// Round 4
// 967.663 us; speedup vs baseline: 7.1606x; 1.6741x over previous
//
#include <hip/hip_runtime.h>
#include <float.h>
#include <math.h>

// ---------------------------------------------------------------------------
// GraphGeneratorX: 3-graph GraphConv network, N=100K nodes, E=3.2M edges.
// Round 4: kill pool_k's global-atomic thundering herd (25K CAS on ONE cache
// line -> ~330us at 0.5% VALUBusy). Max-pool is now two-stage deterministic:
// per-block max row (plain stores) + one small reduce kernel. scan_k is now a
// parallel Hillis-Steele scan instead of 1 thread x 391 iterations.
// ---------------------------------------------------------------------------

#define BBITS   8
#define BINSZ   256
#define MAXP    512
#define SRCBITS 17
#define SRCMASK ((1 << SRCBITS) - 1)
#define EB      512   // blocks for hist/place edge streaming

__device__ __forceinline__ float eluf(float x) {
  return x > 0.0f ? x : (expf(x) - 1.0f);
}

__device__ __forceinline__ void atomicMaxF(float* addr, float val) {
  int* ia = (int*)addr;
  int old = *ia;
  while (__int_as_float(old) < val) {
    int assumed = old;
    old = atomicCAS(ia, assumed, __float_as_int(val));
    if (old == assumed) break;
  }
}

__global__ void init_feats_k(float* feats) {
  int t = threadIdx.x;
  if (t < 32) feats[t] = -FLT_MAX;
}

// ---- binning: histogram + scan + placement ---------------------------------

__global__ void hist_k(const int* __restrict__ ei, int e, int chunk, int P,
                       int* __restrict__ binCnt) {
  __shared__ int h[MAXP];
  int t = threadIdx.x;
  for (int i = t; i < MAXP; i += blockDim.x) h[i] = 0;
  __syncthreads();
  const int* dst = ei + e;
  int lo = blockIdx.x * chunk, hi = min(e, lo + chunk);
  for (int i = lo + t; i < hi; i += blockDim.x) atomicAdd(&h[dst[i] >> BBITS], 1);
  __syncthreads();
  for (int i = t; i < P; i += blockDim.x)
    if (h[i]) atomicAdd(&binCnt[i], h[i]);
}

// parallel inclusive scan over <=MAXP bins; MUST launch with MAXP threads.
__global__ void scan_k(const int* __restrict__ binCnt, int* __restrict__ binOff,
                       int* __restrict__ cursor, int P) {
  __shared__ int buf[MAXP];
  int t = threadIdx.x;
  int v = (t < P) ? binCnt[t] : 0;
  buf[t] = v;
  __syncthreads();
  for (int d = 1; d < MAXP; d <<= 1) {
    int x = (t >= d) ? buf[t - d] : 0;
    __syncthreads();
    buf[t] += x;
    __syncthreads();
  }
  int excl = buf[t] - v;
  if (t < P) {
    binOff[t] = excl;
    cursor[t] = excl;
  }
  if (t == P - 1) binOff[P] = buf[t];
}

__global__ void place_k(const int* __restrict__ ei, int e, int chunk, int P,
                        int* __restrict__ cursor, int* __restrict__ binned) {
  __shared__ int h[MAXP];
  __shared__ int base[MAXP];
  int t = threadIdx.x;
  for (int i = t; i < MAXP; i += blockDim.x) h[i] = 0;
  __syncthreads();
  const int* src = ei;
  const int* dst = ei + e;
  int lo = blockIdx.x * chunk, hi = min(e, lo + chunk);
  for (int i = lo + t; i < hi; i += blockDim.x) atomicAdd(&h[dst[i] >> BBITS], 1);
  __syncthreads();
  for (int i = t; i < P; i += blockDim.x)
    base[i] = h[i] ? atomicAdd(&cursor[i], h[i]) : 0;
  __syncthreads();
  for (int i = t; i < MAXP; i += blockDim.x) h[i] = 0;
  __syncthreads();
  for (int i = lo + t; i < hi; i += blockDim.x) {
    int d = dst[i];
    int bb = d >> BBITS;
    int r = atomicAdd(&h[bb], 1);
    binned[base[bb] + r] = ((d & (BINSZ - 1)) << SRCBITS) | src[i];
  }
}

// ---- LDS-binned aggregation -------------------------------------------------
// grid = (S segments, P bins). LPE lanes cooperate on one edge, each lane
// handling C/LPE channels (slice load + ds_add) -> ~4-way bank conflict max.

template <int C, int LPE, int S, int BLK, bool DEG>
__global__ __launch_bounds__(BLK) void agg_k(const float* __restrict__ x,
                                             const int* __restrict__ binned,
                                             const int* __restrict__ binOff,
                                             float* __restrict__ partial, int P) {
  constexpr int SLAB = BINSZ * (C + (DEG ? 1 : 0));
  constexpr int CL = C / LPE;     // channels per lane
  constexpr int GPB = BLK / LPE;  // edge groups per block
  __shared__ float acc[SLAB];
  int t = threadIdx.x;
  for (int i = t; i < SLAB; i += BLK) acc[i] = 0.f;
  __syncthreads();
  int p = blockIdx.y, s = blockIdx.x;
  int b0 = binOff[p], b1 = binOff[p + 1];
  int seg = (b1 - b0 + S - 1) / S;
  int lo = b0 + s * seg, hi = min(lo + seg, b1);
  int g = t / LPE, j = t % LPE;
#pragma unroll 2
  for (int e = lo + g; e < hi; e += GPB) {
    int pk = binned[e];
    int sI = pk & SRCMASK;
    int loc = pk >> SRCBITS;
    float* a = acc + loc * C + j * CL;
    if (CL == 2) {
      float2 v = *(const float2*)(x + (size_t)sI * C + j * 2);
      atomicAdd(a + 0, v.x);
      atomicAdd(a + 1, v.y);
    } else {
      float4 v = *(const float4*)(x + (size_t)sI * C + j * 4);
      atomicAdd(a + 0, v.x);
      atomicAdd(a + 1, v.y);
      atomicAdd(a + 2, v.z);
      atomicAdd(a + 3, v.w);
    }
    if (DEG && j == 0) atomicAdd(&acc[BINSZ * C + loc], 1.f);
  }
  __syncthreads();
  float4* out = (float4*)(partial + (size_t)(s * P + p) * SLAB);
  const float4* ac = (const float4*)acc;
  for (int i = t; i < SLAB / 4; i += BLK) out[i] = ac[i];
}

// ---- node transforms (fused segment-reduce) ---------------------------------

// o/m conv1: agg over 8 segments of C=2 slabs; x1 = elu(w1r@agg + b1 + w1s@x)
__global__ void node1_om_k(const float* __restrict__ partial, const float* __restrict__ xin,
                           const float* __restrict__ wr, const float* __restrict__ b,
                           const float* __restrict__ wo, float* __restrict__ xout,
                           int n, int P) {
  int i = blockIdx.x * blockDim.x + threadIdx.x;
  if (i >= n) return;
  int p = i >> BBITS, loc = i & (BINSZ - 1);
  float ax = 0.f, ay = 0.f;
#pragma unroll
  for (int s = 0; s < 8; s++) {
    float2 v = *(const float2*)(partial + (size_t)(s * P + p) * (BINSZ * 2) + loc * 2);
    ax += v.x;
    ay += v.y;
  }
  float2 xv = ((const float2*)xin)[i];
  float o_[8];
#pragma unroll
  for (int k = 0; k < 8; k++)
    o_[k] = eluf(wr[2 * k] * ax + wr[2 * k + 1] * ay + b[k] + wo[2 * k] * xv.x + wo[2 * k + 1] * xv.y);
  float4* op = (float4*)(xout + (size_t)i * 8);
  op[0] = make_float4(o_[0], o_[1], o_[2], o_[3]);
  op[1] = make_float4(o_[4], o_[5], o_[6], o_[7]);
}

// c conv1: agg over 8 segments of C=2 slabs + deg channel; x = elu(...16 ch...)
__global__ void node1_c_k(const float* __restrict__ partial, const float* __restrict__ xin,
                          const float* __restrict__ wr, const float* __restrict__ b,
                          const float* __restrict__ wo, float* __restrict__ xout,
                          float* __restrict__ deg, int n, int P) {
  int i = blockIdx.x * blockDim.x + threadIdx.x;
  if (i >= n) return;
  int p = i >> BBITS, loc = i & (BINSZ - 1);
  float ax = 0.f, ay = 0.f, dd = 0.f;
#pragma unroll
  for (int s = 0; s < 8; s++) {
    const float* sl = partial + (size_t)(s * P + p) * (BINSZ * 3);
    float2 v = *(const float2*)(sl + loc * 2);
    ax += v.x;
    ay += v.y;
    dd += sl[BINSZ * 2 + loc];
  }
  float2 xv = ((const float2*)xin)[i];
  float o_[16];
#pragma unroll
  for (int k = 0; k < 16; k++)
    o_[k] = eluf(wr[2 * k] * ax + wr[2 * k + 1] * ay + b[k] + wo[2 * k] * xv.x + wo[2 * k + 1] * xv.y);
  float4* op = (float4*)(xout + (size_t)i * 16);
  op[0] = make_float4(o_[0],  o_[1],  o_[2],  o_[3]);
  op[1] = make_float4(o_[4],  o_[5],  o_[6],  o_[7]);
  op[2] = make_float4(o_[8],  o_[9],  o_[10], o_[11]);
  op[3] = make_float4(o_[12], o_[13], o_[14], o_[15]);
  deg[i] = dd;
}

// o/m conv2 + per-block max pool: agg over 4 segments of C=8 slabs.
// Writes one 16-float block-max row (NO global atomics).
__global__ void pool_k(const float* __restrict__ partial, const float* __restrict__ x8,
                       const float* __restrict__ wr, const float* __restrict__ b,
                       const float* __restrict__ wo, float* __restrict__ bmax,
                       int n, int P) {
  __shared__ float wmax[4][16];
  int i = blockIdx.x * blockDim.x + threadIdx.x;
  float out[16];
  if (i < n) {
    int p = i >> BBITS, loc = i & (BINSZ - 1);
    float a[8] = {0, 0, 0, 0, 0, 0, 0, 0};
#pragma unroll
    for (int s = 0; s < 4; s++) {
      const float4* sl = (const float4*)(partial + (size_t)(s * P + p) * (BINSZ * 8) + loc * 8);
      float4 v0 = sl[0], v1 = sl[1];
      a[0] += v0.x; a[1] += v0.y; a[2] += v0.z; a[3] += v0.w;
      a[4] += v1.x; a[5] += v1.y; a[6] += v1.z; a[7] += v1.w;
    }
    const float4* xp = (const float4*)(x8 + (size_t)i * 8);
    float4 x0 = xp[0], x1 = xp[1];
    float x[8] = {x0.x, x0.y, x0.z, x0.w, x1.x, x1.y, x1.z, x1.w};
#pragma unroll
    for (int k = 0; k < 16; k++) {
      float v = b[k];
#pragma unroll
      for (int j = 0; j < 8; j++) v += wr[8 * k + j] * a[j] + wo[8 * k + j] * x[j];
      out[k] = v;
    }
  } else {
#pragma unroll
    for (int k = 0; k < 16; k++) out[k] = -FLT_MAX;
  }
  int wid = threadIdx.x >> 6, lane = threadIdx.x & 63;
#pragma unroll
  for (int k = 0; k < 16; k++) {
    float v = out[k];
#pragma unroll
    for (int off = 32; off >= 1; off >>= 1) v = fmaxf(v, __shfl_xor(v, off));
    out[k] = v;
  }
  if (lane == 0) {
#pragma unroll
    for (int k = 0; k < 16; k++) wmax[wid][k] = out[k];
  }
  __syncthreads();
  int t = threadIdx.x;
  if (t < 16) {
    float v = fmaxf(fmaxf(wmax[0][t], wmax[1][t]), fmaxf(wmax[2][t], wmax[3][t]));
    bmax[(size_t)blockIdx.x * 16 + t] = v;
  }
}

// reduce bmax[2][nb][16] -> feats[32]; one 512-thread block, deterministic.
__global__ void reduce_feats_k(const float* __restrict__ bmax, float* __restrict__ feats,
                               int nb) {
  __shared__ float red[512];
  int t = threadIdx.x;           // 512 threads
  int ch = t & 31;               // channel 0..31
  int row = t >> 5;              // 0..15
  int g = ch >> 4, k = ch & 15;
  float v = -FLT_MAX;
  for (int blk = row; blk < nb; blk += 16)
    v = fmaxf(v, bmax[((size_t)g * nb + blk) * 16 + k]);
  red[t] = v;
  __syncthreads();
  if (t < 32) {
    float m = red[t];
#pragma unroll
    for (int r = 1; r < 16; r++) m = fmaxf(m, red[t + 32 * r]);
    feats[t] = m;
  }
}

// c final: agg over 4 segments of C=16 slabs; algebraic prior/deg reduction;
// out = sigmoid(conv4) + c
__global__ void final_k(const float* __restrict__ partial, const float* __restrict__ x16,
                        const float* __restrict__ deg, const float* __restrict__ cin,
                        const float* __restrict__ feats, const float* __restrict__ w4r,
                        const float* __restrict__ b4, const float* __restrict__ w4s,
                        float* __restrict__ out, int n, int P) {
  int i = blockIdx.x * blockDim.x + threadIdx.x;
  if (i >= n) return;
  int p = i >> BBITS, loc = i & (BINSZ - 1);
  float ag[16];
#pragma unroll
  for (int k = 0; k < 16; k++) ag[k] = 0.f;
#pragma unroll
  for (int s = 0; s < 4; s++) {
    const float4* sl = (const float4*)(partial + (size_t)(s * P + p) * (BINSZ * 16) + loc * 16);
    float4 v0 = sl[0], v1 = sl[1], v2 = sl[2], v3 = sl[3];
    ag[0]  += v0.x; ag[1]  += v0.y; ag[2]  += v0.z; ag[3]  += v0.w;
    ag[4]  += v1.x; ag[5]  += v1.y; ag[6]  += v1.z; ag[7]  += v1.w;
    ag[8]  += v2.x; ag[9]  += v2.y; ag[10] += v2.z; ag[11] += v2.w;
    ag[12] += v3.x; ag[13] += v3.y; ag[14] += v3.z; ag[15] += v3.w;
  }
  float pr0 = 0.f, pr1 = 0.f, ps0 = 0.f, ps1 = 0.f;
#pragma unroll
  for (int k = 0; k < 32; k++) {
    float pv = feats[k];
    pr0 += w4r[16 + k] * pv;
    pr1 += w4r[48 + 16 + k] * pv;
    ps0 += w4s[16 + k] * pv;
    ps1 += w4s[48 + 16 + k] * pv;
  }
  float d = deg[i];
  float acc0 = b4[0] + ps0 + d * pr0;
  float acc1 = b4[1] + ps1 + d * pr1;
  const float* xv = x16 + (size_t)i * 16;
#pragma unroll
  for (int k = 0; k < 16; k++) {
    float a = ag[k], x = xv[k];
    acc0 += w4r[k] * a + w4s[k] * x;
    acc1 += w4r[48 + k] * a + w4s[48 + k] * x;
  }
  float2 cv = ((const float2*)cin)[i];
  float o0 = 1.0f / (1.0f + expf(-acc0)) + cv.x;
  float o1 = 1.0f / (1.0f + expf(-acc1)) + cv.y;
  ((float2*)out)[i] = make_float2(o0, o1);
}

// ---- fallback path (round-0 atomic kernels, used only if ws too small) ------

__global__ void scatter2_k(const float* __restrict__ x, const int* __restrict__ ei,
                           float* __restrict__ agg, float* __restrict__ deg, int e) {
  int idx = blockIdx.x * blockDim.x + threadIdx.x;
  if (idx >= e) return;
  int s = ei[idx];
  int d = ei[e + idx];
  float2 v = ((const float2*)x)[s];
  atomicAdd(&agg[2 * d + 0], v.x);
  atomicAdd(&agg[2 * d + 1], v.y);
  if (deg) atomicAdd(&deg[d], 1.0f);
}

__global__ void scatter8_k(const float* __restrict__ x, const int* __restrict__ ei,
                           float* __restrict__ agg, int e) {
  int idx = blockIdx.x * blockDim.x + threadIdx.x;
  if (idx >= e) return;
  int s = ei[idx];
  int d = ei[e + idx];
  const float4* xp = (const float4*)(x + (size_t)s * 8);
  float4 v0 = xp[0], v1 = xp[1];
  float* ap = agg + (size_t)d * 8;
  atomicAdd(ap + 0, v0.x); atomicAdd(ap + 1, v0.y);
  atomicAdd(ap + 2, v0.z); atomicAdd(ap + 3, v0.w);
  atomicAdd(ap + 4, v1.x); atomicAdd(ap + 5, v1.y);
  atomicAdd(ap + 6, v1.z); atomicAdd(ap + 7, v1.w);
}

__global__ void scatter16_k(const float* __restrict__ x, const int* __restrict__ ei,
                            float* __restrict__ agg, int e) {
  int idx = blockIdx.x * blockDim.x + threadIdx.x;
  if (idx >= e) return;
  int s = ei[idx];
  int d = ei[e + idx];
  const float4* xp = (const float4*)(x + (size_t)s * 16);
  float4 v0 = xp[0], v1 = xp[1], v2 = xp[2], v3 = xp[3];
  float* ap = agg + (size_t)d * 16;
  atomicAdd(ap + 0,  v0.x); atomicAdd(ap + 1,  v0.y);
  atomicAdd(ap + 2,  v0.z); atomicAdd(ap + 3,  v0.w);
  atomicAdd(ap + 4,  v1.x); atomicAdd(ap + 5,  v1.y);
  atomicAdd(ap + 6,  v1.z); atomicAdd(ap + 7,  v1.w);
  atomicAdd(ap + 8,  v2.x); atomicAdd(ap + 9,  v2.y);
  atomicAdd(ap + 10, v2.z); atomicAdd(ap + 11, v2.w);
  atomicAdd(ap + 12, v3.x); atomicAdd(ap + 13, v3.y);
  atomicAdd(ap + 14, v3.z); atomicAdd(ap + 15, v3.w);
}

__global__ void node_2to8_elu_k(const float* __restrict__ agg, const float* __restrict__ xin,
                                const float* __restrict__ wr, const float* __restrict__ b,
                                const float* __restrict__ wo, float* __restrict__ xout, int n) {
  int i = blockIdx.x * blockDim.x + threadIdx.x;
  if (i >= n) return;
  float2 a = ((const float2*)agg)[i];
  float2 x = ((const float2*)xin)[i];
  float out[8];
#pragma unroll
  for (int k = 0; k < 8; k++)
    out[k] = eluf(wr[2 * k] * a.x + wr[2 * k + 1] * a.y + b[k] + wo[2 * k] * x.x + wo[2 * k + 1] * x.y);
  float4* op = (float4*)(xout + (size_t)i * 8);
  op[0] = make_float4(out[0], out[1], out[2], out[3]);
  op[1] = make_float4(out[4], out[5], out[6], out[7]);
}

__global__ void node_2to16_elu_k(const float* __restrict__ agg, const float* __restrict__ xin,
                                 const float* __restrict__ wr, const float* __restrict__ b,
                                 const float* __restrict__ wo, float* __restrict__ xout, int n) {
  int i = blockIdx.x * blockDim.x + threadIdx.x;
  if (i >= n) return;
  float2 a = ((const float2*)agg)[i];
  float2 x = ((const float2*)xin)[i];
  float out[16];
#pragma unroll
  for (int k = 0; k < 16; k++)
    out[k] = eluf(wr[2 * k] * a.x + wr[2 * k + 1] * a.y + b[k] + wo[2 * k] * x.x + wo[2 * k + 1] * x.y);
  float4* op = (float4*)(xout + (size_t)i * 16);
  op[0] = make_float4(out[0],  out[1],  out[2],  out[3]);
  op[1] = make_float4(out[4],  out[5],  out[6],  out[7]);
  op[2] = make_float4(out[8],  out[9],  out[10], out[11]);
  op[3] = make_float4(out[12], out[13], out[14], out[15]);
}

__global__ void conv2_pool_atomic_k(const float* __restrict__ agg, const float* __restrict__ x8,
                                    const float* __restrict__ wr, const float* __restrict__ b,
                                    const float* __restrict__ wo, float* __restrict__ feat, int n) {
  int i = blockIdx.x * blockDim.x + threadIdx.x;
  float out[16];
  if (i < n) {
    const float4* ap = (const float4*)(agg + (size_t)i * 8);
    const float4* xp = (const float4*)(x8 + (size_t)i * 8);
    float4 a0 = ap[0], a1 = ap[1];
    float4 x0 = xp[0], x1 = xp[1];
    float a[8] = {a0.x, a0.y, a0.z, a0.w, a1.x, a1.y, a1.z, a1.w};
    float x[8] = {x0.x, x0.y, x0.z, x0.w, x1.x, x1.y, x1.z, x1.w};
#pragma unroll
    for (int k = 0; k < 16; k++) {
      float v = b[k];
#pragma unroll
      for (int j = 0; j < 8; j++) v += wr[8 * k + j] * a[j] + wo[8 * k + j] * x[j];
      out[k] = v;
    }
  } else {
#pragma unroll
    for (int k = 0; k < 16; k++) out[k] = -FLT_MAX;
  }
#pragma unroll
  for (int k = 0; k < 16; k++) {
    float v = out[k];
    for (int off = 32; off >= 1; off >>= 1) v = fmaxf(v, __shfl_xor(v, off));
    if ((threadIdx.x & 63) == 0) atomicMaxF(&feat[k], v);
  }
}

__global__ void final_atomic_k(const float* __restrict__ agg16, const float* __restrict__ x16,
                               const float* __restrict__ deg, const float* __restrict__ cin,
                               const float* __restrict__ feats, const float* __restrict__ w4r,
                               const float* __restrict__ b4, const float* __restrict__ w4s,
                               float* __restrict__ out, int n) {
  int i = blockIdx.x * blockDim.x + threadIdx.x;
  if (i >= n) return;
  float pr0 = 0.f, pr1 = 0.f, ps0 = 0.f, ps1 = 0.f;
#pragma unroll
  for (int k = 0; k < 32; k++) {
    float pv = feats[k];
    pr0 += w4r[16 + k] * pv;
    pr1 += w4r[48 + 16 + k] * pv;
    ps0 += w4s[16 + k] * pv;
    ps1 += w4s[48 + 16 + k] * pv;
  }
  float d = deg[i];
  float acc0 = b4[0] + ps0 + d * pr0;
  float acc1 = b4[1] + ps1 + d * pr1;
  const float* ag = agg16 + (size_t)i * 16;
  const float* xv = x16 + (size_t)i * 16;
#pragma unroll
  for (int k = 0; k < 16; k++) {
    float a = ag[k], x = xv[k];
    acc0 += w4r[k] * a + w4s[k] * x;
    acc1 += w4r[48 + k] * a + w4s[48 + k] * x;
  }
  float2 cv = ((const float2*)cin)[i];
  float o0 = 1.0f / (1.0f + expf(-acc0)) + cv.x;
  float o1 = 1.0f / (1.0f + expf(-acc1)) + cv.y;
  ((float2*)out)[i] = make_float2(o0, o1);
}

// ---------------------------------------------------------------------------

extern "C" void kernel_launch(void* const* d_in, const int* in_sizes, int n_in,
                              void* d_out, int out_size, void* d_ws, size_t ws_size,
                              hipStream_t stream) {
  const float* o   = (const float*)d_in[0];
  const float* m   = (const float*)d_in[1];
  const float* c   = (const float*)d_in[2];
  const int* ei_o  = (const int*)d_in[3];
  const int* ei_m  = (const int*)d_in[4];
  const int* ei_c  = (const int*)d_in[5];
  const float* w1r = (const float*)d_in[6];
  const float* w1s = (const float*)d_in[7];
  const float* b1  = (const float*)d_in[8];
  const float* w2r = (const float*)d_in[9];
  const float* w2s = (const float*)d_in[10];
  const float* b2  = (const float*)d_in[11];
  const float* w3r = (const float*)d_in[12];
  const float* w3s = (const float*)d_in[13];
  const float* b3  = (const float*)d_in[14];
  const float* w4r = (const float*)d_in[15];
  const float* w4s = (const float*)d_in[16];
  const float* b4  = (const float*)d_in[17];

  const int n = in_sizes[0] / 2;   // 100000
  const int e = in_sizes[3] / 2;   // 3200000
  const int P = (n + BINSZ - 1) >> BBITS;

  const int BS = 256;
  const int nbn = (n + BS - 1) / BS;

  // ---- workspace layout (binned path) ----
  size_t off = 0;
  int* binned = (int*)d_ws;                         off += (size_t)e * 4;
  float* partial = (float*)((char*)d_ws + off);     off += (size_t)4 * P * BINSZ * 16 * 4;
  float* xh = (float*)((char*)d_ws + off);          off += (size_t)n * 16 * 4;
  float* deg = (float*)((char*)d_ws + off);         off += (size_t)n * 4;
  float* bmax = (float*)((char*)d_ws + off);        off += (size_t)2 * nbn * 16 * 4;
  int* binCnt = (int*)((char*)d_ws + off);          off += MAXP * 4;
  int* binOff = (int*)((char*)d_ws + off);          off += (MAXP + 1) * 4;
  int* cursor = (int*)((char*)d_ws + off);          off += MAXP * 4;
  float* feats = (float*)((char*)d_ws + off);       off += 32 * 4;

  bool binned_ok = (off <= ws_size) && (P <= MAXP) && (n <= (1 << SRCBITS));

  if (!binned_ok) {
    // round-0 atomic fallback
    float* agg_f   = (float*)d_ws;
    float* xh_f    = agg_f + (size_t)n * 16;
    float* deg_f   = xh_f + (size_t)n * 16;
    float* feats_f = deg_f + n;
    const int nb_e = (e + BS - 1) / BS;
    init_feats_k<<<1, 64, 0, stream>>>(feats_f);
    hipMemsetAsync(agg_f, 0, (size_t)n * 2 * sizeof(float), stream);
    scatter2_k<<<nb_e, BS, 0, stream>>>(o, ei_o, agg_f, nullptr, e);
    node_2to8_elu_k<<<nbn, BS, 0, stream>>>(agg_f, o, w1r, b1, w1s, xh_f, n);
    hipMemsetAsync(agg_f, 0, (size_t)n * 8 * sizeof(float), stream);
    scatter8_k<<<nb_e, BS, 0, stream>>>(xh_f, ei_o, agg_f, e);
    conv2_pool_atomic_k<<<nbn, BS, 0, stream>>>(agg_f, xh_f, w2r, b2, w2s, feats_f, n);
    hipMemsetAsync(agg_f, 0, (size_t)n * 2 * sizeof(float), stream);
    scatter2_k<<<nb_e, BS, 0, stream>>>(m, ei_m, agg_f, nullptr, e);
    node_2to8_elu_k<<<nbn, BS, 0, stream>>>(agg_f, m, w1r, b1, w1s, xh_f, n);
    hipMemsetAsync(agg_f, 0, (size_t)n * 8 * sizeof(float), stream);
    scatter8_k<<<nb_e, BS, 0, stream>>>(xh_f, ei_m, agg_f, e);
    conv2_pool_atomic_k<<<nbn, BS, 0, stream>>>(agg_f, xh_f, w2r, b2, w2s, feats_f + 16, n);
    hipMemsetAsync(agg_f, 0, (size_t)n * 2 * sizeof(float), stream);
    hipMemsetAsync(deg_f, 0, (size_t)n * sizeof(float), stream);
    scatter2_k<<<nb_e, BS, 0, stream>>>(c, ei_c, agg_f, deg_f, e);
    node_2to16_elu_k<<<nbn, BS, 0, stream>>>(agg_f, c, w3r, b3, w3s, xh_f, n);
    hipMemsetAsync(agg_f, 0, (size_t)n * 16 * sizeof(float), stream);
    scatter16_k<<<nb_e, BS, 0, stream>>>(xh_f, ei_c, agg_f, e);
    final_atomic_k<<<nbn, BS, 0, stream>>>(agg_f, xh_f, deg_f, c, feats_f, w4r, b4, w4s,
                                           (float*)d_out, n);
    return;
  }

  const int chunk = (e + EB - 1) / EB;

  // ---- graph o -> bmax[0]
  hipMemsetAsync(binCnt, 0, P * sizeof(int), stream);
  hist_k<<<EB, BS, 0, stream>>>(ei_o, e, chunk, P, binCnt);
  scan_k<<<1, MAXP, 0, stream>>>(binCnt, binOff, cursor, P);
  place_k<<<EB, BS, 0, stream>>>(ei_o, e, chunk, P, cursor, binned);
  agg_k<2, 1, 8, 256, false><<<dim3(8, P), 256, 0, stream>>>(o, binned, binOff, partial, P);
  node1_om_k<<<nbn, BS, 0, stream>>>(partial, o, w1r, b1, w1s, xh, n, P);
  agg_k<8, 4, 4, 256, false><<<dim3(4, P), 256, 0, stream>>>(xh, binned, binOff, partial, P);
  pool_k<<<nbn, BS, 0, stream>>>(partial, xh, w2r, b2, w2s, bmax, n, P);

  // ---- graph m -> bmax[1]
  hipMemsetAsync(binCnt, 0, P * sizeof(int), stream);
  hist_k<<<EB, BS, 0, stream>>>(ei_m, e, chunk, P, binCnt);
  scan_k<<<1, MAXP, 0, stream>>>(binCnt, binOff, cursor, P);
  place_k<<<EB, BS, 0, stream>>>(ei_m, e, chunk, P, cursor, binned);
  agg_k<2, 1, 8, 256, false><<<dim3(8, P), 256, 0, stream>>>(m, binned, binOff, partial, P);
  node1_om_k<<<nbn, BS, 0, stream>>>(partial, m, w1r, b1, w1s, xh, n, P);
  agg_k<8, 4, 4, 256, false><<<dim3(4, P), 256, 0, stream>>>(xh, binned, binOff, partial, P);
  pool_k<<<nbn, BS, 0, stream>>>(partial, xh, w2r, b2, w2s, bmax + (size_t)nbn * 16, n, P);

  // feats[32] from both graphs' block maxima
  reduce_feats_k<<<1, 512, 0, stream>>>(bmax, feats, nbn);

  // ---- graph c
  hipMemsetAsync(binCnt, 0, P * sizeof(int), stream);
  hist_k<<<EB, BS, 0, stream>>>(ei_c, e, chunk, P, binCnt);
  scan_k<<<1, MAXP, 0, stream>>>(binCnt, binOff, cursor, P);
  place_k<<<EB, BS, 0, stream>>>(ei_c, e, chunk, P, cursor, binned);
  agg_k<2, 1, 8, 256, true><<<dim3(8, P), 256, 0, stream>>>(c, binned, binOff, partial, P);
  node1_c_k<<<nbn, BS, 0, stream>>>(partial, c, w3r, b3, w3s, xh, deg, n, P);
  agg_k<16, 4, 4, 256, false><<<dim3(4, P), 256, 0, stream>>>(xh, binned, binOff, partial, P);
  final_k<<<nbn, BS, 0, stream>>>(partial, xh, deg, c, feats, w4r, b4, w4s,
                                  (float*)d_out, n, P);
}

// Round 5
// 691.873 us; speedup vs baseline: 10.0149x; 1.3986x over previous
//
#include <hip/hip_runtime.h>
#include <float.h>
#include <math.h>

// ---------------------------------------------------------------------------
// GraphGeneratorX: 3-graph GraphConv network, N=100K nodes, E=3.2M edges.
// Round 5: kill the C=16 aggregation (296us: 64B/edge random gathers from a
// 6.4MB table, L2-miss latency-bound). W4r@segment_sum(xh) == segment_sum of
// the 2-dim projection W4r@xh  -> project per-node in node1_c_k, aggregate C=2
// from a 0.8MB L2-resident table. xh16 never materialized. C8 aggs: S=4->8.
// ---------------------------------------------------------------------------

#define BBITS   8
#define BINSZ   256
#define MAXP    512
#define SRCBITS 17
#define SRCMASK ((1 << SRCBITS) - 1)
#define EB      512   // blocks for hist/place edge streaming

__device__ __forceinline__ float eluf(float x) {
  return x > 0.0f ? x : (expf(x) - 1.0f);
}

__device__ __forceinline__ void atomicMaxF(float* addr, float val) {
  int* ia = (int*)addr;
  int old = *ia;
  while (__int_as_float(old) < val) {
    int assumed = old;
    old = atomicCAS(ia, assumed, __float_as_int(val));
    if (old == assumed) break;
  }
}

__global__ void init_feats_k(float* feats) {
  int t = threadIdx.x;
  if (t < 32) feats[t] = -FLT_MAX;
}

// ---- binning: histogram + scan + placement ---------------------------------

__global__ void hist_k(const int* __restrict__ ei, int e, int chunk, int P,
                       int* __restrict__ binCnt) {
  __shared__ int h[MAXP];
  int t = threadIdx.x;
  for (int i = t; i < MAXP; i += blockDim.x) h[i] = 0;
  __syncthreads();
  const int* dst = ei + e;
  int lo = blockIdx.x * chunk, hi = min(e, lo + chunk);
  for (int i = lo + t; i < hi; i += blockDim.x) atomicAdd(&h[dst[i] >> BBITS], 1);
  __syncthreads();
  for (int i = t; i < P; i += blockDim.x)
    if (h[i]) atomicAdd(&binCnt[i], h[i]);
}

// parallel inclusive scan over <=MAXP bins; MUST launch with MAXP threads.
__global__ void scan_k(const int* __restrict__ binCnt, int* __restrict__ binOff,
                       int* __restrict__ cursor, int P) {
  __shared__ int buf[MAXP];
  int t = threadIdx.x;
  int v = (t < P) ? binCnt[t] : 0;
  buf[t] = v;
  __syncthreads();
  for (int d = 1; d < MAXP; d <<= 1) {
    int x = (t >= d) ? buf[t - d] : 0;
    __syncthreads();
    buf[t] += x;
    __syncthreads();
  }
  int excl = buf[t] - v;
  if (t < P) {
    binOff[t] = excl;
    cursor[t] = excl;
  }
  if (t == P - 1) binOff[P] = buf[t];
}

__global__ void place_k(const int* __restrict__ ei, int e, int chunk, int P,
                        int* __restrict__ cursor, int* __restrict__ binned) {
  __shared__ int h[MAXP];
  __shared__ int base[MAXP];
  int t = threadIdx.x;
  for (int i = t; i < MAXP; i += blockDim.x) h[i] = 0;
  __syncthreads();
  const int* src = ei;
  const int* dst = ei + e;
  int lo = blockIdx.x * chunk, hi = min(e, lo + chunk);
  for (int i = lo + t; i < hi; i += blockDim.x) atomicAdd(&h[dst[i] >> BBITS], 1);
  __syncthreads();
  for (int i = t; i < P; i += blockDim.x)
    base[i] = h[i] ? atomicAdd(&cursor[i], h[i]) : 0;
  __syncthreads();
  for (int i = t; i < MAXP; i += blockDim.x) h[i] = 0;
  __syncthreads();
  for (int i = lo + t; i < hi; i += blockDim.x) {
    int d = dst[i];
    int bb = d >> BBITS;
    int r = atomicAdd(&h[bb], 1);
    binned[base[bb] + r] = ((d & (BINSZ - 1)) << SRCBITS) | src[i];
  }
}

// ---- LDS-binned aggregation -------------------------------------------------
// grid = (S segments, P bins). LPE lanes cooperate on one edge, each lane
// handling C/LPE channels (slice load + ds_add) -> ~4-way bank conflict max.

template <int C, int LPE, int S, int BLK, bool DEG>
__global__ __launch_bounds__(BLK) void agg_k(const float* __restrict__ x,
                                             const int* __restrict__ binned,
                                             const int* __restrict__ binOff,
                                             float* __restrict__ partial, int P) {
  constexpr int SLAB = BINSZ * (C + (DEG ? 1 : 0));
  constexpr int CL = C / LPE;     // channels per lane
  constexpr int GPB = BLK / LPE;  // edge groups per block
  __shared__ float acc[SLAB];
  int t = threadIdx.x;
  for (int i = t; i < SLAB; i += BLK) acc[i] = 0.f;
  __syncthreads();
  int p = blockIdx.y, s = blockIdx.x;
  int b0 = binOff[p], b1 = binOff[p + 1];
  int seg = (b1 - b0 + S - 1) / S;
  int lo = b0 + s * seg, hi = min(lo + seg, b1);
  int g = t / LPE, j = t % LPE;
#pragma unroll 4
  for (int e = lo + g; e < hi; e += GPB) {
    int pk = binned[e];
    int sI = pk & SRCMASK;
    int loc = pk >> SRCBITS;
    float* a = acc + loc * C + j * CL;
    if (CL == 2) {
      float2 v = *(const float2*)(x + (size_t)sI * C + j * 2);
      atomicAdd(a + 0, v.x);
      atomicAdd(a + 1, v.y);
    } else {
      float4 v = *(const float4*)(x + (size_t)sI * C + j * 4);
      atomicAdd(a + 0, v.x);
      atomicAdd(a + 1, v.y);
      atomicAdd(a + 2, v.z);
      atomicAdd(a + 3, v.w);
    }
    if (DEG && j == 0) atomicAdd(&acc[BINSZ * C + loc], 1.f);
  }
  __syncthreads();
  float4* out = (float4*)(partial + (size_t)(s * P + p) * SLAB);
  const float4* ac = (const float4*)acc;
  for (int i = t; i < SLAB / 4; i += BLK) out[i] = ac[i];
}

// ---- node transforms (fused segment-reduce) ---------------------------------

// o/m conv1: agg over 8 segments of C=2 slabs; x1 = elu(w1r@agg + b1 + w1s@x)
__global__ void node1_om_k(const float* __restrict__ partial, const float* __restrict__ xin,
                           const float* __restrict__ wr, const float* __restrict__ b,
                           const float* __restrict__ wo, float* __restrict__ xout,
                           int n, int P) {
  int i = blockIdx.x * blockDim.x + threadIdx.x;
  if (i >= n) return;
  int p = i >> BBITS, loc = i & (BINSZ - 1);
  float ax = 0.f, ay = 0.f;
#pragma unroll
  for (int s = 0; s < 8; s++) {
    float2 v = *(const float2*)(partial + (size_t)(s * P + p) * (BINSZ * 2) + loc * 2);
    ax += v.x;
    ay += v.y;
  }
  float2 xv = ((const float2*)xin)[i];
  float o_[8];
#pragma unroll
  for (int k = 0; k < 8; k++)
    o_[k] = eluf(wr[2 * k] * ax + wr[2 * k + 1] * ay + b[k] + wo[2 * k] * xv.x + wo[2 * k + 1] * xv.y);
  float4* op = (float4*)(xout + (size_t)i * 8);
  op[0] = make_float4(o_[0], o_[1], o_[2], o_[3]);
  op[1] = make_float4(o_[4], o_[5], o_[6], o_[7]);
}

// c conv1: agg over 8 segments of C=2 slabs + deg channel; computes the 16-dim
// elu(conv3) in registers, then stores only its 2-dim projections:
//   y_rel  = W4r[:, :16] @ x16   (gets aggregated over edges afterwards)
//   y_root = W4s[:, :16] @ x16   (per-node root term of conv4)
__global__ void node1_c_k(const float* __restrict__ partial, const float* __restrict__ xin,
                          const float* __restrict__ wr, const float* __restrict__ b,
                          const float* __restrict__ wo,
                          const float* __restrict__ w4r, const float* __restrict__ w4s,
                          float* __restrict__ yrel, float* __restrict__ yroot,
                          float* __restrict__ deg, int n, int P) {
  int i = blockIdx.x * blockDim.x + threadIdx.x;
  if (i >= n) return;
  int p = i >> BBITS, loc = i & (BINSZ - 1);
  float ax = 0.f, ay = 0.f, dd = 0.f;
#pragma unroll
  for (int s = 0; s < 8; s++) {
    const float* sl = partial + (size_t)(s * P + p) * (BINSZ * 3);
    float2 v = *(const float2*)(sl + loc * 2);
    ax += v.x;
    ay += v.y;
    dd += sl[BINSZ * 2 + loc];
  }
  float2 xv = ((const float2*)xin)[i];
  float yr0 = 0.f, yr1 = 0.f, ys0 = 0.f, ys1 = 0.f;
#pragma unroll
  for (int k = 0; k < 16; k++) {
    float v = eluf(wr[2 * k] * ax + wr[2 * k + 1] * ay + b[k] + wo[2 * k] * xv.x + wo[2 * k + 1] * xv.y);
    yr0 += w4r[k] * v;
    yr1 += w4r[48 + k] * v;
    ys0 += w4s[k] * v;
    ys1 += w4s[48 + k] * v;
  }
  ((float2*)yrel)[i] = make_float2(yr0, yr1);
  ((float2*)yroot)[i] = make_float2(ys0, ys1);
  deg[i] = dd;
}

// o/m conv2 + per-block max pool: agg over 8 segments of C=8 slabs.
// Writes one 16-float block-max row (NO global atomics).
__global__ void pool_k(const float* __restrict__ partial, const float* __restrict__ x8,
                       const float* __restrict__ wr, const float* __restrict__ b,
                       const float* __restrict__ wo, float* __restrict__ bmax,
                       int n, int P) {
  __shared__ float wmax[4][16];
  int i = blockIdx.x * blockDim.x + threadIdx.x;
  float out[16];
  if (i < n) {
    int p = i >> BBITS, loc = i & (BINSZ - 1);
    float a[8] = {0, 0, 0, 0, 0, 0, 0, 0};
#pragma unroll
    for (int s = 0; s < 8; s++) {
      const float4* sl = (const float4*)(partial + (size_t)(s * P + p) * (BINSZ * 8) + loc * 8);
      float4 v0 = sl[0], v1 = sl[1];
      a[0] += v0.x; a[1] += v0.y; a[2] += v0.z; a[3] += v0.w;
      a[4] += v1.x; a[5] += v1.y; a[6] += v1.z; a[7] += v1.w;
    }
    const float4* xp = (const float4*)(x8 + (size_t)i * 8);
    float4 x0 = xp[0], x1 = xp[1];
    float x[8] = {x0.x, x0.y, x0.z, x0.w, x1.x, x1.y, x1.z, x1.w};
#pragma unroll
    for (int k = 0; k < 16; k++) {
      float v = b[k];
#pragma unroll
      for (int j = 0; j < 8; j++) v += wr[8 * k + j] * a[j] + wo[8 * k + j] * x[j];
      out[k] = v;
    }
  } else {
#pragma unroll
    for (int k = 0; k < 16; k++) out[k] = -FLT_MAX;
  }
  int wid = threadIdx.x >> 6, lane = threadIdx.x & 63;
#pragma unroll
  for (int k = 0; k < 16; k++) {
    float v = out[k];
#pragma unroll
    for (int off = 32; off >= 1; off >>= 1) v = fmaxf(v, __shfl_xor(v, off));
    out[k] = v;
  }
  if (lane == 0) {
#pragma unroll
    for (int k = 0; k < 16; k++) wmax[wid][k] = out[k];
  }
  __syncthreads();
  int t = threadIdx.x;
  if (t < 16) {
    float v = fmaxf(fmaxf(wmax[0][t], wmax[1][t]), fmaxf(wmax[2][t], wmax[3][t]));
    bmax[(size_t)blockIdx.x * 16 + t] = v;
  }
}

// reduce bmax[2][nb][16] -> feats[32]; one 512-thread block, deterministic.
__global__ void reduce_feats_k(const float* __restrict__ bmax, float* __restrict__ feats,
                               int nb) {
  __shared__ float red[512];
  int t = threadIdx.x;           // 512 threads
  int ch = t & 31;               // channel 0..31
  int row = t >> 5;              // 0..15
  int g = ch >> 4, k = ch & 15;
  float v = -FLT_MAX;
  for (int blk = row; blk < nb; blk += 16)
    v = fmaxf(v, bmax[((size_t)g * nb + blk) * 16 + k]);
  red[t] = v;
  __syncthreads();
  if (t < 32) {
    float m = red[t];
#pragma unroll
    for (int r = 1; r < 16; r++) m = fmaxf(m, red[t + 32 * r]);
    feats[t] = m;
  }
}

// c final: agg over 8 segments of C=2 slabs (projected y_rel); algebraic
// prior/deg reduction; out = sigmoid(b4 + prior_s + d*prior_r + agg_y + y_root) + c
__global__ void final_k(const float* __restrict__ partial, const float* __restrict__ yroot,
                        const float* __restrict__ deg, const float* __restrict__ cin,
                        const float* __restrict__ feats, const float* __restrict__ w4r,
                        const float* __restrict__ b4, const float* __restrict__ w4s,
                        float* __restrict__ out, int n, int P) {
  int i = blockIdx.x * blockDim.x + threadIdx.x;
  if (i >= n) return;
  int p = i >> BBITS, loc = i & (BINSZ - 1);
  float ay0 = 0.f, ay1 = 0.f;
#pragma unroll
  for (int s = 0; s < 8; s++) {
    float2 v = *(const float2*)(partial + (size_t)(s * P + p) * (BINSZ * 2) + loc * 2);
    ay0 += v.x;
    ay1 += v.y;
  }
  float pr0 = 0.f, pr1 = 0.f, ps0 = 0.f, ps1 = 0.f;
#pragma unroll
  for (int k = 0; k < 32; k++) {
    float pv = feats[k];
    pr0 += w4r[16 + k] * pv;
    pr1 += w4r[48 + 16 + k] * pv;
    ps0 += w4s[16 + k] * pv;
    ps1 += w4s[48 + 16 + k] * pv;
  }
  float d = deg[i];
  float2 yr = ((const float2*)yroot)[i];
  float acc0 = b4[0] + ps0 + d * pr0 + ay0 + yr.x;
  float acc1 = b4[1] + ps1 + d * pr1 + ay1 + yr.y;
  float2 cv = ((const float2*)cin)[i];
  float o0 = 1.0f / (1.0f + expf(-acc0)) + cv.x;
  float o1 = 1.0f / (1.0f + expf(-acc1)) + cv.y;
  ((float2*)out)[i] = make_float2(o0, o1);
}

// ---- fallback path (round-0 atomic kernels, used only if ws too small) ------

__global__ void scatter2_k(const float* __restrict__ x, const int* __restrict__ ei,
                           float* __restrict__ agg, float* __restrict__ deg, int e) {
  int idx = blockIdx.x * blockDim.x + threadIdx.x;
  if (idx >= e) return;
  int s = ei[idx];
  int d = ei[e + idx];
  float2 v = ((const float2*)x)[s];
  atomicAdd(&agg[2 * d + 0], v.x);
  atomicAdd(&agg[2 * d + 1], v.y);
  if (deg) atomicAdd(&deg[d], 1.0f);
}

__global__ void scatter8_k(const float* __restrict__ x, const int* __restrict__ ei,
                           float* __restrict__ agg, int e) {
  int idx = blockIdx.x * blockDim.x + threadIdx.x;
  if (idx >= e) return;
  int s = ei[idx];
  int d = ei[e + idx];
  const float4* xp = (const float4*)(x + (size_t)s * 8);
  float4 v0 = xp[0], v1 = xp[1];
  float* ap = agg + (size_t)d * 8;
  atomicAdd(ap + 0, v0.x); atomicAdd(ap + 1, v0.y);
  atomicAdd(ap + 2, v0.z); atomicAdd(ap + 3, v0.w);
  atomicAdd(ap + 4, v1.x); atomicAdd(ap + 5, v1.y);
  atomicAdd(ap + 6, v1.z); atomicAdd(ap + 7, v1.w);
}

__global__ void scatter16_k(const float* __restrict__ x, const int* __restrict__ ei,
                            float* __restrict__ agg, int e) {
  int idx = blockIdx.x * blockDim.x + threadIdx.x;
  if (idx >= e) return;
  int s = ei[idx];
  int d = ei[e + idx];
  const float4* xp = (const float4*)(x + (size_t)s * 16);
  float4 v0 = xp[0], v1 = xp[1], v2 = xp[2], v3 = xp[3];
  float* ap = agg + (size_t)d * 16;
  atomicAdd(ap + 0,  v0.x); atomicAdd(ap + 1,  v0.y);
  atomicAdd(ap + 2,  v0.z); atomicAdd(ap + 3,  v0.w);
  atomicAdd(ap + 4,  v1.x); atomicAdd(ap + 5,  v1.y);
  atomicAdd(ap + 6,  v1.z); atomicAdd(ap + 7,  v1.w);
  atomicAdd(ap + 8,  v2.x); atomicAdd(ap + 9,  v2.y);
  atomicAdd(ap + 10, v2.z); atomicAdd(ap + 11, v2.w);
  atomicAdd(ap + 12, v3.x); atomicAdd(ap + 13, v3.y);
  atomicAdd(ap + 14, v3.z); atomicAdd(ap + 15, v3.w);
}

__global__ void node_2to8_elu_k(const float* __restrict__ agg, const float* __restrict__ xin,
                                const float* __restrict__ wr, const float* __restrict__ b,
                                const float* __restrict__ wo, float* __restrict__ xout, int n) {
  int i = blockIdx.x * blockDim.x + threadIdx.x;
  if (i >= n) return;
  float2 a = ((const float2*)agg)[i];
  float2 x = ((const float2*)xin)[i];
  float out[8];
#pragma unroll
  for (int k = 0; k < 8; k++)
    out[k] = eluf(wr[2 * k] * a.x + wr[2 * k + 1] * a.y + b[k] + wo[2 * k] * x.x + wo[2 * k + 1] * x.y);
  float4* op = (float4*)(xout + (size_t)i * 8);
  op[0] = make_float4(out[0], out[1], out[2], out[3]);
  op[1] = make_float4(out[4], out[5], out[6], out[7]);
}

__global__ void node_2to16_elu_k(const float* __restrict__ agg, const float* __restrict__ xin,
                                 const float* __restrict__ wr, const float* __restrict__ b,
                                 const float* __restrict__ wo, float* __restrict__ xout, int n) {
  int i = blockIdx.x * blockDim.x + threadIdx.x;
  if (i >= n) return;
  float2 a = ((const float2*)agg)[i];
  float2 x = ((const float2*)xin)[i];
  float out[16];
#pragma unroll
  for (int k = 0; k < 16; k++)
    out[k] = eluf(wr[2 * k] * a.x + wr[2 * k + 1] * a.y + b[k] + wo[2 * k] * x.x + wo[2 * k + 1] * x.y);
  float4* op = (float4*)(xout + (size_t)i * 16);
  op[0] = make_float4(out[0],  out[1],  out[2],  out[3]);
  op[1] = make_float4(out[4],  out[5],  out[6],  out[7]);
  op[2] = make_float4(out[8],  out[9],  out[10], out[11]);
  op[3] = make_float4(out[12], out[13], out[14], out[15]);
}

__global__ void conv2_pool_atomic_k(const float* __restrict__ agg, const float* __restrict__ x8,
                                    const float* __restrict__ wr, const float* __restrict__ b,
                                    const float* __restrict__ wo, float* __restrict__ feat, int n) {
  int i = blockIdx.x * blockDim.x + threadIdx.x;
  float out[16];
  if (i < n) {
    const float4* ap = (const float4*)(agg + (size_t)i * 8);
    const float4* xp = (const float4*)(x8 + (size_t)i * 8);
    float4 a0 = ap[0], a1 = ap[1];
    float4 x0 = xp[0], x1 = xp[1];
    float a[8] = {a0.x, a0.y, a0.z, a0.w, a1.x, a1.y, a1.z, a1.w};
    float x[8] = {x0.x, x0.y, x0.z, x0.w, x1.x, x1.y, x1.z, x1.w};
#pragma unroll
    for (int k = 0; k < 16; k++) {
      float v = b[k];
#pragma unroll
      for (int j = 0; j < 8; j++) v += wr[8 * k + j] * a[j] + wo[8 * k + j] * x[j];
      out[k] = v;
    }
  } else {
#pragma unroll
    for (int k = 0; k < 16; k++) out[k] = -FLT_MAX;
  }
#pragma unroll
  for (int k = 0; k < 16; k++) {
    float v = out[k];
    for (int off = 32; off >= 1; off >>= 1) v = fmaxf(v, __shfl_xor(v, off));
    if ((threadIdx.x & 63) == 0) atomicMaxF(&feat[k], v);
  }
}

__global__ void final_atomic_k(const float* __restrict__ agg16, const float* __restrict__ x16,
                               const float* __restrict__ deg, const float* __restrict__ cin,
                               const float* __restrict__ feats, const float* __restrict__ w4r,
                               const float* __restrict__ b4, const float* __restrict__ w4s,
                               float* __restrict__ out, int n) {
  int i = blockIdx.x * blockDim.x + threadIdx.x;
  if (i >= n) return;
  float pr0 = 0.f, pr1 = 0.f, ps0 = 0.f, ps1 = 0.f;
#pragma unroll
  for (int k = 0; k < 32; k++) {
    float pv = feats[k];
    pr0 += w4r[16 + k] * pv;
    pr1 += w4r[48 + 16 + k] * pv;
    ps0 += w4s[16 + k] * pv;
    ps1 += w4s[48 + 16 + k] * pv;
  }
  float d = deg[i];
  float acc0 = b4[0] + ps0 + d * pr0;
  float acc1 = b4[1] + ps1 + d * pr1;
  const float* ag = agg16 + (size_t)i * 16;
  const float* xv = x16 + (size_t)i * 16;
#pragma unroll
  for (int k = 0; k < 16; k++) {
    float a = ag[k], x = xv[k];
    acc0 += w4r[k] * a + w4s[k] * x;
    acc1 += w4r[48 + k] * a + w4s[48 + k] * x;
  }
  float2 cv = ((const float2*)cin)[i];
  float o0 = 1.0f / (1.0f + expf(-acc0)) + cv.x;
  float o1 = 1.0f / (1.0f + expf(-acc1)) + cv.y;
  ((float2*)out)[i] = make_float2(o0, o1);
}

// ---------------------------------------------------------------------------

extern "C" void kernel_launch(void* const* d_in, const int* in_sizes, int n_in,
                              void* d_out, int out_size, void* d_ws, size_t ws_size,
                              hipStream_t stream) {
  const float* o   = (const float*)d_in[0];
  const float* m   = (const float*)d_in[1];
  const float* c   = (const float*)d_in[2];
  const int* ei_o  = (const int*)d_in[3];
  const int* ei_m  = (const int*)d_in[4];
  const int* ei_c  = (const int*)d_in[5];
  const float* w1r = (const float*)d_in[6];
  const float* w1s = (const float*)d_in[7];
  const float* b1  = (const float*)d_in[8];
  const float* w2r = (const float*)d_in[9];
  const float* w2s = (const float*)d_in[10];
  const float* b2  = (const float*)d_in[11];
  const float* w3r = (const float*)d_in[12];
  const float* w3s = (const float*)d_in[13];
  const float* b3  = (const float*)d_in[14];
  const float* w4r = (const float*)d_in[15];
  const float* w4s = (const float*)d_in[16];
  const float* b4  = (const float*)d_in[17];

  const int n = in_sizes[0] / 2;   // 100000
  const int e = in_sizes[3] / 2;   // 3200000
  const int P = (n + BINSZ - 1) >> BBITS;

  const int BS = 256;
  const int nbn = (n + BS - 1) / BS;

  // ---- workspace layout (binned path) ----
  size_t off = 0;
  int* binned = (int*)d_ws;                         off += (size_t)e * 4;
  float* partial = (float*)((char*)d_ws + off);     off += (size_t)8 * P * BINSZ * 8 * 4;
  float* xh = (float*)((char*)d_ws + off);          off += (size_t)n * 16 * 4;
  float* deg = (float*)((char*)d_ws + off);         off += (size_t)n * 4;
  float* bmax = (float*)((char*)d_ws + off);        off += (size_t)2 * nbn * 16 * 4;
  int* binCnt = (int*)((char*)d_ws + off);          off += MAXP * 4;
  int* binOff = (int*)((char*)d_ws + off);          off += (MAXP + 1) * 4;
  int* cursor = (int*)((char*)d_ws + off);          off += MAXP * 4;
  float* feats = (float*)((char*)d_ws + off);       off += 32 * 4;

  // sub-layout inside the xh block for graph c (runs after o/m are done):
  float* yrel  = xh;                 // n*2 floats
  float* yroot = xh + (size_t)2 * n; // n*2 floats

  bool binned_ok = (off <= ws_size) && (P <= MAXP) && (n <= (1 << SRCBITS));

  if (!binned_ok) {
    // round-0 atomic fallback
    float* agg_f   = (float*)d_ws;
    float* xh_f    = agg_f + (size_t)n * 16;
    float* deg_f   = xh_f + (size_t)n * 16;
    float* feats_f = deg_f + n;
    const int nb_e = (e + BS - 1) / BS;
    init_feats_k<<<1, 64, 0, stream>>>(feats_f);
    hipMemsetAsync(agg_f, 0, (size_t)n * 2 * sizeof(float), stream);
    scatter2_k<<<nb_e, BS, 0, stream>>>(o, ei_o, agg_f, nullptr, e);
    node_2to8_elu_k<<<nbn, BS, 0, stream>>>(agg_f, o, w1r, b1, w1s, xh_f, n);
    hipMemsetAsync(agg_f, 0, (size_t)n * 8 * sizeof(float), stream);
    scatter8_k<<<nb_e, BS, 0, stream>>>(xh_f, ei_o, agg_f, e);
    conv2_pool_atomic_k<<<nbn, BS, 0, stream>>>(agg_f, xh_f, w2r, b2, w2s, feats_f, n);
    hipMemsetAsync(agg_f, 0, (size_t)n * 2 * sizeof(float), stream);
    scatter2_k<<<nb_e, BS, 0, stream>>>(m, ei_m, agg_f, nullptr, e);
    node_2to8_elu_k<<<nbn, BS, 0, stream>>>(agg_f, m, w1r, b1, w1s, xh_f, n);
    hipMemsetAsync(agg_f, 0, (size_t)n * 8 * sizeof(float), stream);
    scatter8_k<<<nb_e, BS, 0, stream>>>(xh_f, ei_m, agg_f, e);
    conv2_pool_atomic_k<<<nbn, BS, 0, stream>>>(agg_f, xh_f, w2r, b2, w2s, feats_f + 16, n);
    hipMemsetAsync(agg_f, 0, (size_t)n * 2 * sizeof(float), stream);
    hipMemsetAsync(deg_f, 0, (size_t)n * sizeof(float), stream);
    scatter2_k<<<nb_e, BS, 0, stream>>>(c, ei_c, agg_f, deg_f, e);
    node_2to16_elu_k<<<nbn, BS, 0, stream>>>(agg_f, c, w3r, b3, w3s, xh_f, n);
    hipMemsetAsync(agg_f, 0, (size_t)n * 16 * sizeof(float), stream);
    scatter16_k<<<nb_e, BS, 0, stream>>>(xh_f, ei_c, agg_f, e);
    final_atomic_k<<<nbn, BS, 0, stream>>>(agg_f, xh_f, deg_f, c, feats_f, w4r, b4, w4s,
                                           (float*)d_out, n);
    return;
  }

  const int chunk = (e + EB - 1) / EB;

  // ---- graph o -> bmax[0]
  hipMemsetAsync(binCnt, 0, P * sizeof(int), stream);
  hist_k<<<EB, BS, 0, stream>>>(ei_o, e, chunk, P, binCnt);
  scan_k<<<1, MAXP, 0, stream>>>(binCnt, binOff, cursor, P);
  place_k<<<EB, BS, 0, stream>>>(ei_o, e, chunk, P, cursor, binned);
  agg_k<2, 1, 8, 256, false><<<dim3(8, P), 256, 0, stream>>>(o, binned, binOff, partial, P);
  node1_om_k<<<nbn, BS, 0, stream>>>(partial, o, w1r, b1, w1s, xh, n, P);
  agg_k<8, 4, 8, 256, false><<<dim3(8, P), 256, 0, stream>>>(xh, binned, binOff, partial, P);
  pool_k<<<nbn, BS, 0, stream>>>(partial, xh, w2r, b2, w2s, bmax, n, P);

  // ---- graph m -> bmax[1]
  hipMemsetAsync(binCnt, 0, P * sizeof(int), stream);
  hist_k<<<EB, BS, 0, stream>>>(ei_m, e, chunk, P, binCnt);
  scan_k<<<1, MAXP, 0, stream>>>(binCnt, binOff, cursor, P);
  place_k<<<EB, BS, 0, stream>>>(ei_m, e, chunk, P, cursor, binned);
  agg_k<2, 1, 8, 256, false><<<dim3(8, P), 256, 0, stream>>>(m, binned, binOff, partial, P);
  node1_om_k<<<nbn, BS, 0, stream>>>(partial, m, w1r, b1, w1s, xh, n, P);
  agg_k<8, 4, 8, 256, false><<<dim3(8, P), 256, 0, stream>>>(xh, binned, binOff, partial, P);
  pool_k<<<nbn, BS, 0, stream>>>(partial, xh, w2r, b2, w2s, bmax + (size_t)nbn * 16, n, P);

  // feats[32] from both graphs' block maxima
  reduce_feats_k<<<1, 512, 0, stream>>>(bmax, feats, nbn);

  // ---- graph c
  hipMemsetAsync(binCnt, 0, P * sizeof(int), stream);
  hist_k<<<EB, BS, 0, stream>>>(ei_c, e, chunk, P, binCnt);
  scan_k<<<1, MAXP, 0, stream>>>(binCnt, binOff, cursor, P);
  place_k<<<EB, BS, 0, stream>>>(ei_c, e, chunk, P, cursor, binned);
  agg_k<2, 1, 8, 256, true><<<dim3(8, P), 256, 0, stream>>>(c, binned, binOff, partial, P);
  node1_c_k<<<nbn, BS, 0, stream>>>(partial, c, w3r, b3, w3s, w4r, w4s,
                                    yrel, yroot, deg, n, P);
  agg_k<2, 1, 8, 256, false><<<dim3(8, P), 256, 0, stream>>>(yrel, binned, binOff, partial, P);
  final_k<<<nbn, BS, 0, stream>>>(partial, yroot, deg, c, feats, w4r, b4, w4s,
                                  (float*)d_out, n, P);
}

// Round 6
// 455.415 us; speedup vs baseline: 15.2148x; 1.5192x over previous
//
#include <hip/hip_runtime.h>
#include <float.h>
#include <math.h>

// ---------------------------------------------------------------------------
// GraphGeneratorX: 3-graph GraphConv network, N=100K nodes, E=3.2M edges.
// Round 6: LDS atomics measured at ~3.4 cy/lane-op (cost ∝ C across rounds:
// C16=296us, C8=142us). Pipeline currency = LDS-atomic ops/edge: was 34.
// Now: full counting-sort to CSR per graph (place 2 ops + sort 2 ops = 12
// total), then ALL aggregations are atomic-free register gathers fused with
// their node transforms (no partial slabs at all).
// ---------------------------------------------------------------------------

#define BBITS   8
#define BINSZ   256
#define MAXP    512
#define SRCBITS 17
#define SRCMASK ((1 << SRCBITS) - 1)
#define EB      256    // blocks for place edge streaming
#define CAP     12288  // per-bin slot capacity (mean 8184, sigma~90)

__device__ __forceinline__ float eluf(float x) {
  return x > 0.0f ? x : (expf(x) - 1.0f);
}

__device__ __forceinline__ void atomicMaxF(float* addr, float val) {
  int* ia = (int*)addr;
  int old = *ia;
  while (__int_as_float(old) < val) {
    int assumed = old;
    old = atomicCAS(ia, assumed, __float_as_int(val));
    if (old == assumed) break;
  }
}

__global__ void init_feats_k(float* feats) {
  int t = threadIdx.x;
  if (t < 32) feats[t] = -FLT_MAX;
}

// ---- CSR build: place (bin slots) + scan + in-bin counting sort ------------

// reserve per-(block,bin) space via global cursor; write packed (loc,src).
__global__ void place_k(const int* __restrict__ ei, int e, int chunk, int P,
                        int* __restrict__ binCnt, int* __restrict__ packed) {
  __shared__ int h[MAXP];
  __shared__ int base[MAXP];
  int t = threadIdx.x;
  for (int i = t; i < MAXP; i += blockDim.x) h[i] = 0;
  __syncthreads();
  const int* src = ei;
  const int* dst = ei + e;
  int lo = blockIdx.x * chunk, hi = min(e, lo + chunk);
  for (int i = lo + t; i < hi; i += blockDim.x) atomicAdd(&h[dst[i] >> BBITS], 1);
  __syncthreads();
  for (int i = t; i < P; i += blockDim.x)
    base[i] = h[i] ? atomicAdd(&binCnt[i], h[i]) : 0;
  __syncthreads();
  for (int i = t; i < MAXP; i += blockDim.x) h[i] = 0;
  __syncthreads();
  for (int i = lo + t; i < hi; i += blockDim.x) {
    int d = dst[i];
    int bb = d >> BBITS;
    int r = atomicAdd(&h[bb], 1);
    int idx = base[bb] + r;
    if (idx < CAP) packed[(size_t)bb * CAP + idx] = ((d & (BINSZ - 1)) << SRCBITS) | src[i];
  }
}

// parallel scan of bin counts -> binBase; also rowptr[n] = total.
__global__ void scan_k(const int* __restrict__ binCnt, int* __restrict__ binBase,
                       int* __restrict__ rowptr, int P, int n) {
  __shared__ int buf[MAXP];
  int t = threadIdx.x;  // MAXP threads
  int v = (t < P) ? min(binCnt[t], CAP) : 0;
  buf[t] = v;
  __syncthreads();
  for (int d = 1; d < MAXP; d <<= 1) {
    int x = (t >= d) ? buf[t - d] : 0;
    __syncthreads();
    buf[t] += x;
    __syncthreads();
  }
  if (t < P) binBase[t] = buf[t] - v;
  if (t == P - 1) {
    binBase[P] = buf[t];
    rowptr[n] = buf[t];
  }
}

// one block per bin: count per node, scan, write rowptr, rank-scatter srcs.
__global__ __launch_bounds__(512) void sort_k(const int* __restrict__ binCnt,
                                              const int* __restrict__ binBase,
                                              const int* __restrict__ packed,
                                              int* __restrict__ sortedSrc,
                                              int* __restrict__ rowptr, int n) {
  __shared__ int cnt[BINSZ];
  __shared__ int pos[BINSZ];
  __shared__ int sc[BINSZ];
  int p = blockIdx.x, t = threadIdx.x;
  int nEd = min(binCnt[p], CAP);
  int b0 = binBase[p];
  if (t < BINSZ) cnt[t] = 0;
  __syncthreads();
  const int* pk = packed + (size_t)p * CAP;
  for (int i = t; i < nEd; i += 512) atomicAdd(&cnt[pk[i] >> SRCBITS], 1);
  __syncthreads();
  if (t < BINSZ) sc[t] = cnt[t];
  __syncthreads();
  for (int d = 1; d < BINSZ; d <<= 1) {
    int x = 0;
    if (t < BINSZ && t >= d) x = sc[t - d];
    __syncthreads();
    if (t < BINSZ) sc[t] += x;
    __syncthreads();
  }
  if (t < BINSZ) {
    int excl = sc[t] - cnt[t];
    int node = p * BINSZ + t;
    if (node < n) rowptr[node] = b0 + excl;
    pos[t] = excl;
  }
  __syncthreads();
  for (int i = t; i < nEd; i += 512) {
    int v = pk[i];
    int r = atomicAdd(&pos[v >> SRCBITS], 1);
    sortedSrc[b0 + r] = v & SRCMASK;
  }
}

// ---- atomic-free fused aggregation kernels (4 lanes per node) ---------------

// o/m conv1: agg c=2 over CSR + elu(2->8), write xh8
__global__ void agg1om_k(const int* __restrict__ rowptr, const int* __restrict__ src,
                         const float* __restrict__ x, const float* __restrict__ wr,
                         const float* __restrict__ b, const float* __restrict__ wo,
                         float* __restrict__ xh8, int n) {
  int tid = blockIdx.x * blockDim.x + threadIdx.x;
  int i = tid >> 2, j = tid & 3;
  if (i >= n) return;
  int r0 = rowptr[i], r1 = rowptr[i + 1];
  float ax = 0.f, ay = 0.f;
  for (int e = r0 + j; e < r1; e += 4) {
    int s = src[e];
    float2 v = ((const float2*)x)[s];
    ax += v.x;
    ay += v.y;
  }
  ax += __shfl_xor(ax, 1); ax += __shfl_xor(ax, 2);
  ay += __shfl_xor(ay, 1); ay += __shfl_xor(ay, 2);
  float2 xv = ((const float2*)x)[i];
  int k0 = 2 * j, k1 = 2 * j + 1;
  float o0 = eluf(wr[2 * k0] * ax + wr[2 * k0 + 1] * ay + b[k0] + wo[2 * k0] * xv.x + wo[2 * k0 + 1] * xv.y);
  float o1 = eluf(wr[2 * k1] * ax + wr[2 * k1 + 1] * ay + b[k1] + wo[2 * k1] * xv.x + wo[2 * k1 + 1] * xv.y);
  ((float2*)(xh8 + (size_t)i * 8))[j] = make_float2(o0, o1);
}

// o/m conv2 + max-pool: agg c=8 over CSR, conv 8->16, wave+block max -> bmax
__global__ void agg2pool_k(const int* __restrict__ rowptr, const int* __restrict__ src,
                           const float* __restrict__ x8, const float* __restrict__ wr,
                           const float* __restrict__ b, const float* __restrict__ wo,
                           float* __restrict__ bmax, int n) {
  __shared__ float wmax[4][16];
  int tid = blockIdx.x * blockDim.x + threadIdx.x;
  int i = tid >> 2, j = tid & 3;
  float a[8] = {0, 0, 0, 0, 0, 0, 0, 0};
  bool valid = (i < n);
  if (valid) {
    int r0 = rowptr[i], r1 = rowptr[i + 1];
    for (int e = r0 + j; e < r1; e += 4) {
      int s = src[e];
      const float4* xp = (const float4*)(x8 + (size_t)s * 8);
      float4 v0 = xp[0], v1 = xp[1];
      a[0] += v0.x; a[1] += v0.y; a[2] += v0.z; a[3] += v0.w;
      a[4] += v1.x; a[5] += v1.y; a[6] += v1.z; a[7] += v1.w;
    }
  }
#pragma unroll
  for (int k = 0; k < 8; k++) {
    a[k] += __shfl_xor(a[k], 1);
    a[k] += __shfl_xor(a[k], 2);
  }
  float out[4];
  if (valid) {
    const float4* xp = (const float4*)(x8 + (size_t)i * 8);
    float4 x0 = xp[0], x1 = xp[1];
    float xx[8] = {x0.x, x0.y, x0.z, x0.w, x1.x, x1.y, x1.z, x1.w};
#pragma unroll
    for (int kk = 0; kk < 4; kk++) {
      int k = 4 * j + kk;
      float v = b[k];
#pragma unroll
      for (int l = 0; l < 8; l++) v += wr[8 * k + l] * a[l] + wo[8 * k + l] * xx[l];
      out[kk] = v;
    }
  } else {
    out[0] = out[1] = out[2] = out[3] = -FLT_MAX;
  }
#pragma unroll
  for (int kk = 0; kk < 4; kk++) {
    float v = out[kk];
    v = fmaxf(v, __shfl_xor(v, 4));
    v = fmaxf(v, __shfl_xor(v, 8));
    v = fmaxf(v, __shfl_xor(v, 16));
    v = fmaxf(v, __shfl_xor(v, 32));
    out[kk] = v;
  }
  int t = threadIdx.x, wid = t >> 6, lane = t & 63;
  if (lane < 4) {
#pragma unroll
    for (int kk = 0; kk < 4; kk++) wmax[wid][4 * lane + kk] = out[kk];
  }
  __syncthreads();
  if (t < 16) {
    float v = fmaxf(fmaxf(wmax[0][t], wmax[1][t]), fmaxf(wmax[2][t], wmax[3][t]));
    bmax[(size_t)blockIdx.x * 16 + t] = v;
  }
}

// reduce bmax[2][nb][16] -> feats[32]; one 512-thread block, deterministic.
__global__ void reduce_feats_k(const float* __restrict__ bmax, float* __restrict__ feats,
                               int nb) {
  __shared__ float red[512];
  int t = threadIdx.x;
  int ch = t & 31;
  int row = t >> 5;
  int g = ch >> 4, k = ch & 15;
  float v = -FLT_MAX;
  for (int blk = row; blk < nb; blk += 16)
    v = fmaxf(v, bmax[((size_t)g * nb + blk) * 16 + k]);
  red[t] = v;
  __syncthreads();
  if (t < 32) {
    float m = red[t];
#pragma unroll
    for (int r = 1; r < 16; r++) m = fmaxf(m, red[t + 32 * r]);
    feats[t] = m;
  }
}

// c conv1: agg c=2 over CSR + elu(2->16 in regs) + project to yrel/yroot (2-dim)
__global__ void agg1c_k(const int* __restrict__ rowptr, const int* __restrict__ src,
                        const float* __restrict__ cin, const float* __restrict__ wr,
                        const float* __restrict__ b, const float* __restrict__ wo,
                        const float* __restrict__ w4r, const float* __restrict__ w4s,
                        float* __restrict__ yrel, float* __restrict__ yroot, int n) {
  int tid = blockIdx.x * blockDim.x + threadIdx.x;
  int i = tid >> 2, j = tid & 3;
  if (i >= n) return;
  int r0 = rowptr[i], r1 = rowptr[i + 1];
  float ax = 0.f, ay = 0.f;
  for (int e = r0 + j; e < r1; e += 4) {
    int s = src[e];
    float2 v = ((const float2*)cin)[s];
    ax += v.x;
    ay += v.y;
  }
  ax += __shfl_xor(ax, 1); ax += __shfl_xor(ax, 2);
  ay += __shfl_xor(ay, 1); ay += __shfl_xor(ay, 2);
  float2 xv = ((const float2*)cin)[i];
  float yr0 = 0.f, yr1 = 0.f, ys0 = 0.f, ys1 = 0.f;
#pragma unroll
  for (int kk = 0; kk < 4; kk++) {
    int k = 4 * j + kk;
    float v = eluf(wr[2 * k] * ax + wr[2 * k + 1] * ay + b[k] + wo[2 * k] * xv.x + wo[2 * k + 1] * xv.y);
    yr0 += w4r[k] * v;
    yr1 += w4r[48 + k] * v;
    ys0 += w4s[k] * v;
    ys1 += w4s[48 + k] * v;
  }
  yr0 += __shfl_xor(yr0, 1); yr0 += __shfl_xor(yr0, 2);
  yr1 += __shfl_xor(yr1, 1); yr1 += __shfl_xor(yr1, 2);
  ys0 += __shfl_xor(ys0, 1); ys0 += __shfl_xor(ys0, 2);
  ys1 += __shfl_xor(ys1, 1); ys1 += __shfl_xor(ys1, 2);
  if (j == 0) ((float2*)yrel)[i] = make_float2(yr0, yr1);
  if (j == 1) ((float2*)yroot)[i] = make_float2(ys0, ys1);
}

// c final: agg c=2 (yrel) over CSR; deg = row length; sigmoid + c
__global__ void aggfinal_k(const int* __restrict__ rowptr, const int* __restrict__ src,
                           const float* __restrict__ yrel, const float* __restrict__ yroot,
                           const float* __restrict__ cin, const float* __restrict__ feats,
                           const float* __restrict__ w4r, const float* __restrict__ b4,
                           const float* __restrict__ w4s, float* __restrict__ out, int n) {
  int tid = blockIdx.x * blockDim.x + threadIdx.x;
  int i = tid >> 2, j = tid & 3;
  if (i >= n) return;
  int r0 = rowptr[i], r1 = rowptr[i + 1];
  float ay0 = 0.f, ay1 = 0.f;
  for (int e = r0 + j; e < r1; e += 4) {
    int s = src[e];
    float2 v = ((const float2*)yrel)[s];
    ay0 += v.x;
    ay1 += v.y;
  }
  ay0 += __shfl_xor(ay0, 1); ay0 += __shfl_xor(ay0, 2);
  ay1 += __shfl_xor(ay1, 1); ay1 += __shfl_xor(ay1, 2);
  if (j != 0) return;
  float pr0 = 0.f, pr1 = 0.f, ps0 = 0.f, ps1 = 0.f;
#pragma unroll
  for (int k = 0; k < 32; k++) {
    float pv = feats[k];
    pr0 += w4r[16 + k] * pv;
    pr1 += w4r[64 + k] * pv;
    ps0 += w4s[16 + k] * pv;
    ps1 += w4s[64 + k] * pv;
  }
  float d = (float)(r1 - r0);
  float2 yrt = ((const float2*)yroot)[i];
  float acc0 = b4[0] + ps0 + d * pr0 + ay0 + yrt.x;
  float acc1 = b4[1] + ps1 + d * pr1 + ay1 + yrt.y;
  float2 cv = ((const float2*)cin)[i];
  float o0 = 1.0f / (1.0f + expf(-acc0)) + cv.x;
  float o1 = 1.0f / (1.0f + expf(-acc1)) + cv.y;
  ((float2*)out)[i] = make_float2(o0, o1);
}

// ---- fallback path (round-0 atomic kernels, used only if ws too small) ------

__global__ void scatter2_k(const float* __restrict__ x, const int* __restrict__ ei,
                           float* __restrict__ agg, float* __restrict__ deg, int e) {
  int idx = blockIdx.x * blockDim.x + threadIdx.x;
  if (idx >= e) return;
  int s = ei[idx];
  int d = ei[e + idx];
  float2 v = ((const float2*)x)[s];
  atomicAdd(&agg[2 * d + 0], v.x);
  atomicAdd(&agg[2 * d + 1], v.y);
  if (deg) atomicAdd(&deg[d], 1.0f);
}

__global__ void scatter8_k(const float* __restrict__ x, const int* __restrict__ ei,
                           float* __restrict__ agg, int e) {
  int idx = blockIdx.x * blockDim.x + threadIdx.x;
  if (idx >= e) return;
  int s = ei[idx];
  int d = ei[e + idx];
  const float4* xp = (const float4*)(x + (size_t)s * 8);
  float4 v0 = xp[0], v1 = xp[1];
  float* ap = agg + (size_t)d * 8;
  atomicAdd(ap + 0, v0.x); atomicAdd(ap + 1, v0.y);
  atomicAdd(ap + 2, v0.z); atomicAdd(ap + 3, v0.w);
  atomicAdd(ap + 4, v1.x); atomicAdd(ap + 5, v1.y);
  atomicAdd(ap + 6, v1.z); atomicAdd(ap + 7, v1.w);
}

__global__ void scatter16_k(const float* __restrict__ x, const int* __restrict__ ei,
                            float* __restrict__ agg, int e) {
  int idx = blockIdx.x * blockDim.x + threadIdx.x;
  if (idx >= e) return;
  int s = ei[idx];
  int d = ei[e + idx];
  const float4* xp = (const float4*)(x + (size_t)s * 16);
  float4 v0 = xp[0], v1 = xp[1], v2 = xp[2], v3 = xp[3];
  float* ap = agg + (size_t)d * 16;
  atomicAdd(ap + 0,  v0.x); atomicAdd(ap + 1,  v0.y);
  atomicAdd(ap + 2,  v0.z); atomicAdd(ap + 3,  v0.w);
  atomicAdd(ap + 4,  v1.x); atomicAdd(ap + 5,  v1.y);
  atomicAdd(ap + 6,  v1.z); atomicAdd(ap + 7,  v1.w);
  atomicAdd(ap + 8,  v2.x); atomicAdd(ap + 9,  v2.y);
  atomicAdd(ap + 10, v2.z); atomicAdd(ap + 11, v2.w);
  atomicAdd(ap + 12, v3.x); atomicAdd(ap + 13, v3.y);
  atomicAdd(ap + 14, v3.z); atomicAdd(ap + 15, v3.w);
}

__global__ void node_2to8_elu_k(const float* __restrict__ agg, const float* __restrict__ xin,
                                const float* __restrict__ wr, const float* __restrict__ b,
                                const float* __restrict__ wo, float* __restrict__ xout, int n) {
  int i = blockIdx.x * blockDim.x + threadIdx.x;
  if (i >= n) return;
  float2 a = ((const float2*)agg)[i];
  float2 x = ((const float2*)xin)[i];
  float out[8];
#pragma unroll
  for (int k = 0; k < 8; k++)
    out[k] = eluf(wr[2 * k] * a.x + wr[2 * k + 1] * a.y + b[k] + wo[2 * k] * x.x + wo[2 * k + 1] * x.y);
  float4* op = (float4*)(xout + (size_t)i * 8);
  op[0] = make_float4(out[0], out[1], out[2], out[3]);
  op[1] = make_float4(out[4], out[5], out[6], out[7]);
}

__global__ void node_2to16_elu_k(const float* __restrict__ agg, const float* __restrict__ xin,
                                 const float* __restrict__ wr, const float* __restrict__ b,
                                 const float* __restrict__ wo, float* __restrict__ xout, int n) {
  int i = blockIdx.x * blockDim.x + threadIdx.x;
  if (i >= n) return;
  float2 a = ((const float2*)agg)[i];
  float2 x = ((const float2*)xin)[i];
  float out[16];
#pragma unroll
  for (int k = 0; k < 16; k++)
    out[k] = eluf(wr[2 * k] * a.x + wr[2 * k + 1] * a.y + b[k] + wo[2 * k] * x.x + wo[2 * k + 1] * x.y);
  float4* op = (float4*)(xout + (size_t)i * 16);
  op[0] = make_float4(out[0],  out[1],  out[2],  out[3]);
  op[1] = make_float4(out[4],  out[5],  out[6],  out[7]);
  op[2] = make_float4(out[8],  out[9],  out[10], out[11]);
  op[3] = make_float4(out[12], out[13], out[14], out[15]);
}

__global__ void conv2_pool_atomic_k(const float* __restrict__ agg, const float* __restrict__ x8,
                                    const float* __restrict__ wr, const float* __restrict__ b,
                                    const float* __restrict__ wo, float* __restrict__ feat, int n) {
  int i = blockIdx.x * blockDim.x + threadIdx.x;
  float out[16];
  if (i < n) {
    const float4* ap = (const float4*)(agg + (size_t)i * 8);
    const float4* xp = (const float4*)(x8 + (size_t)i * 8);
    float4 a0 = ap[0], a1 = ap[1];
    float4 x0 = xp[0], x1 = xp[1];
    float a[8] = {a0.x, a0.y, a0.z, a0.w, a1.x, a1.y, a1.z, a1.w};
    float x[8] = {x0.x, x0.y, x0.z, x0.w, x1.x, x1.y, x1.z, x1.w};
#pragma unroll
    for (int k = 0; k < 16; k++) {
      float v = b[k];
#pragma unroll
      for (int j = 0; j < 8; j++) v += wr[8 * k + j] * a[j] + wo[8 * k + j] * x[j];
      out[k] = v;
    }
  } else {
#pragma unroll
    for (int k = 0; k < 16; k++) out[k] = -FLT_MAX;
  }
#pragma unroll
  for (int k = 0; k < 16; k++) {
    float v = out[k];
    for (int off = 32; off >= 1; off >>= 1) v = fmaxf(v, __shfl_xor(v, off));
    if ((threadIdx.x & 63) == 0) atomicMaxF(&feat[k], v);
  }
}

__global__ void final_atomic_k(const float* __restrict__ agg16, const float* __restrict__ x16,
                               const float* __restrict__ deg, const float* __restrict__ cin,
                               const float* __restrict__ feats, const float* __restrict__ w4r,
                               const float* __restrict__ b4, const float* __restrict__ w4s,
                               float* __restrict__ out, int n) {
  int i = blockIdx.x * blockDim.x + threadIdx.x;
  if (i >= n) return;
  float pr0 = 0.f, pr1 = 0.f, ps0 = 0.f, ps1 = 0.f;
#pragma unroll
  for (int k = 0; k < 32; k++) {
    float pv = feats[k];
    pr0 += w4r[16 + k] * pv;
    pr1 += w4r[48 + 16 + k] * pv;
    ps0 += w4s[16 + k] * pv;
    ps1 += w4s[48 + 16 + k] * pv;
  }
  float d = deg[i];
  float acc0 = b4[0] + ps0 + d * pr0;
  float acc1 = b4[1] + ps1 + d * pr1;
  const float* ag = agg16 + (size_t)i * 16;
  const float* xv = x16 + (size_t)i * 16;
#pragma unroll
  for (int k = 0; k < 16; k++) {
    float a = ag[k], x = xv[k];
    acc0 += w4r[k] * a + w4s[k] * x;
    acc1 += w4r[48 + k] * a + w4s[48 + k] * x;
  }
  float2 cv = ((const float2*)cin)[i];
  float o0 = 1.0f / (1.0f + expf(-acc0)) + cv.x;
  float o1 = 1.0f / (1.0f + expf(-acc1)) + cv.y;
  ((float2*)out)[i] = make_float2(o0, o1);
}

// ---------------------------------------------------------------------------

extern "C" void kernel_launch(void* const* d_in, const int* in_sizes, int n_in,
                              void* d_out, int out_size, void* d_ws, size_t ws_size,
                              hipStream_t stream) {
  const float* o   = (const float*)d_in[0];
  const float* m   = (const float*)d_in[1];
  const float* c   = (const float*)d_in[2];
  const int* ei_o  = (const int*)d_in[3];
  const int* ei_m  = (const int*)d_in[4];
  const int* ei_c  = (const int*)d_in[5];
  const float* w1r = (const float*)d_in[6];
  const float* w1s = (const float*)d_in[7];
  const float* b1  = (const float*)d_in[8];
  const float* w2r = (const float*)d_in[9];
  const float* w2s = (const float*)d_in[10];
  const float* b2  = (const float*)d_in[11];
  const float* w3r = (const float*)d_in[12];
  const float* w3s = (const float*)d_in[13];
  const float* b3  = (const float*)d_in[14];
  const float* w4r = (const float*)d_in[15];
  const float* w4s = (const float*)d_in[16];
  const float* b4  = (const float*)d_in[17];

  const int n = in_sizes[0] / 2;   // 100000
  const int e = in_sizes[3] / 2;   // 3200000
  const int P = (n + BINSZ - 1) >> BBITS;

  const int BS = 256;
  const int nbn = (n + BS - 1) / BS;
  const int nb4 = (4 * n + BS - 1) / BS;   // blocks for 4-lane-per-node kernels

  // ---- workspace layout (CSR path) ----
  size_t off = 0;
  int* packed = (int*)d_ws;                         off += (size_t)P * CAP * 4;
  int* sortedSrc = (int*)((char*)d_ws + off);       off += (size_t)e * 4;
  int* rowptr = (int*)((char*)d_ws + off);          off += (size_t)(n + 1) * 4;
  float* xh8 = (float*)((char*)d_ws + off);         off += (size_t)n * 8 * 4;
  float* bmax = (float*)((char*)d_ws + off);        off += (size_t)2 * nb4 * 16 * 4;
  int* binCnt = (int*)((char*)d_ws + off);          off += MAXP * 4;
  int* binBase = (int*)((char*)d_ws + off);         off += (MAXP + 1) * 4;
  float* feats = (float*)((char*)d_ws + off);       off += 32 * 4;

  // c-graph projections reuse the xh8 block:
  float* yrel  = xh8;                  // n*2 floats
  float* yroot = xh8 + (size_t)2 * n;  // n*2 floats

  bool csr_ok = (off <= ws_size) && (P <= MAXP) && (n <= (1 << SRCBITS)) &&
                (n <= P * BINSZ);

  if (!csr_ok) {
    // round-0 atomic fallback
    float* agg_f   = (float*)d_ws;
    float* xh_f    = agg_f + (size_t)n * 16;
    float* deg_f   = xh_f + (size_t)n * 16;
    float* feats_f = deg_f + n;
    const int nb_e = (e + BS - 1) / BS;
    init_feats_k<<<1, 64, 0, stream>>>(feats_f);
    hipMemsetAsync(agg_f, 0, (size_t)n * 2 * sizeof(float), stream);
    scatter2_k<<<nb_e, BS, 0, stream>>>(o, ei_o, agg_f, nullptr, e);
    node_2to8_elu_k<<<nbn, BS, 0, stream>>>(agg_f, o, w1r, b1, w1s, xh_f, n);
    hipMemsetAsync(agg_f, 0, (size_t)n * 8 * sizeof(float), stream);
    scatter8_k<<<nb_e, BS, 0, stream>>>(xh_f, ei_o, agg_f, e);
    conv2_pool_atomic_k<<<nbn, BS, 0, stream>>>(agg_f, xh_f, w2r, b2, w2s, feats_f, n);
    hipMemsetAsync(agg_f, 0, (size_t)n * 2 * sizeof(float), stream);
    scatter2_k<<<nb_e, BS, 0, stream>>>(m, ei_m, agg_f, nullptr, e);
    node_2to8_elu_k<<<nbn, BS, 0, stream>>>(agg_f, m, w1r, b1, w1s, xh_f, n);
    hipMemsetAsync(agg_f, 0, (size_t)n * 8 * sizeof(float), stream);
    scatter8_k<<<nb_e, BS, 0, stream>>>(xh_f, ei_m, agg_f, e);
    conv2_pool_atomic_k<<<nbn, BS, 0, stream>>>(agg_f, xh_f, w2r, b2, w2s, feats_f + 16, n);
    hipMemsetAsync(agg_f, 0, (size_t)n * 2 * sizeof(float), stream);
    hipMemsetAsync(deg_f, 0, (size_t)n * sizeof(float), stream);
    scatter2_k<<<nb_e, BS, 0, stream>>>(c, ei_c, agg_f, deg_f, e);
    node_2to16_elu_k<<<nbn, BS, 0, stream>>>(agg_f, c, w3r, b3, w3s, xh_f, n);
    hipMemsetAsync(agg_f, 0, (size_t)n * 16 * sizeof(float), stream);
    scatter16_k<<<nb_e, BS, 0, stream>>>(xh_f, ei_c, agg_f, e);
    final_atomic_k<<<nbn, BS, 0, stream>>>(agg_f, xh_f, deg_f, c, feats_f, w4r, b4, w4s,
                                           (float*)d_out, n);
    return;
  }

  const int chunk = (e + EB - 1) / EB;

  // ---- graph o -> bmax[0]
  hipMemsetAsync(binCnt, 0, P * sizeof(int), stream);
  place_k<<<EB, BS, 0, stream>>>(ei_o, e, chunk, P, binCnt, packed);
  scan_k<<<1, MAXP, 0, stream>>>(binCnt, binBase, rowptr, P, n);
  sort_k<<<P, 512, 0, stream>>>(binCnt, binBase, packed, sortedSrc, rowptr, n);
  agg1om_k<<<nb4, BS, 0, stream>>>(rowptr, sortedSrc, o, w1r, b1, w1s, xh8, n);
  agg2pool_k<<<nb4, BS, 0, stream>>>(rowptr, sortedSrc, xh8, w2r, b2, w2s, bmax, n);

  // ---- graph m -> bmax[1]
  hipMemsetAsync(binCnt, 0, P * sizeof(int), stream);
  place_k<<<EB, BS, 0, stream>>>(ei_m, e, chunk, P, binCnt, packed);
  scan_k<<<1, MAXP, 0, stream>>>(binCnt, binBase, rowptr, P, n);
  sort_k<<<P, 512, 0, stream>>>(binCnt, binBase, packed, sortedSrc, rowptr, n);
  agg1om_k<<<nb4, BS, 0, stream>>>(rowptr, sortedSrc, m, w1r, b1, w1s, xh8, n);
  agg2pool_k<<<nb4, BS, 0, stream>>>(rowptr, sortedSrc, xh8, w2r, b2, w2s,
                                     bmax + (size_t)nb4 * 16, n);

  // feats[32] from both graphs' block maxima
  reduce_feats_k<<<1, 512, 0, stream>>>(bmax, feats, nb4);

  // ---- graph c
  hipMemsetAsync(binCnt, 0, P * sizeof(int), stream);
  place_k<<<EB, BS, 0, stream>>>(ei_c, e, chunk, P, binCnt, packed);
  scan_k<<<1, MAXP, 0, stream>>>(binCnt, binBase, rowptr, P, n);
  sort_k<<<P, 512, 0, stream>>>(binCnt, binBase, packed, sortedSrc, rowptr, n);
  agg1c_k<<<nb4, BS, 0, stream>>>(rowptr, sortedSrc, c, w3r, b3, w3s, w4r, w4s,
                                  yrel, yroot, n);
  aggfinal_k<<<nb4, BS, 0, stream>>>(rowptr, sortedSrc, yrel, yroot, c, feats,
                                     w4r, b4, w4s, (float*)d_out, n);
}